// Round 5
// baseline (425.990 us; speedup 1.0000x reference)
//
#include <hip/hip_runtime.h>
#include <hip/hip_bf16.h>

#define TT 2048
#define DM 2048
#define NH 16
#define KVH 4
#define HD 128

typedef __attribute__((ext_vector_type(8))) short bs8;
typedef __attribute__((ext_vector_type(4))) float fx4;
typedef __attribute__((ext_vector_type(4))) unsigned short us4;
typedef __attribute__((ext_vector_type(8))) unsigned short us8;

#if __has_builtin(__builtin_amdgcn_exp2f)
#define EXP2(x) __builtin_amdgcn_exp2f(x)
#else
#define EXP2(x) exp2f(x)
#endif

__device__ inline unsigned short f2b(float f) {
  __hip_bfloat16 h = __float2bfloat16(f);
  return *reinterpret_cast<unsigned short*>(&h);
}

__device__ inline float b2f(unsigned short u) {
  unsigned int v = ((unsigned int)u) << 16;
  return *reinterpret_cast<float*>(&v);
}

__device__ inline void gld_lds16(const ushort* g, ushort* l) {
  __builtin_amdgcn_global_load_lds(
      (const __attribute__((address_space(1))) void*)g,
      (__attribute__((address_space(3))) void*)l,
      16, 0, 0);
}

// ---------------- prep: weight transposes + x cast, one dispatch ----------------
// z=0: Wqkvt[3072][2048] from Wq|Wk|Wv   z=1: Wot[2048][2048] from Wo
// z=2: x fp32 -> bf16 cast (linear)
__global__ __launch_bounds__(256) void prep_kernel(
    const float* __restrict__ x, const float* __restrict__ Wq,
    const float* __restrict__ Wk, const float* __restrict__ Wv,
    const float* __restrict__ Wo, ushort* __restrict__ xb,
    ushort* __restrict__ Wqkvt, ushort* __restrict__ Wot) {
  int tx = threadIdx.x, ty = threadIdx.y;  // block (32,8)
  if (blockIdx.z == 2) {
    int lin = (blockIdx.y * 96 + blockIdx.x) * 256 + ty * 32 + tx;
#pragma unroll
    for (int it = 0; it < 2; ++it) {
      int i = lin + it * (6144 * 256);
      if (i < (TT * 2 * DM) / 4) {
        float4 v = ((const float4*)x)[i];
        us4 o = {f2b(v.x), f2b(v.y), f2b(v.z), f2b(v.w)};
        ((us4*)xb)[i] = o;
      }
    }
    return;
  }
  __shared__ float t[32][33];
  int n0 = blockIdx.x * 32, k0 = blockIdx.y * 32;
  if (blockIdx.z == 0) {
    const float* src;
    int srcN, col0;
    if (n0 < 2048) { src = Wq; srcN = 2048; col0 = n0; }
    else if (n0 < 2560) { src = Wk; srcN = 512; col0 = n0 - 2048; }
    else { src = Wv; srcN = 512; col0 = n0 - 2560; }
    for (int jj = 0; jj < 4; ++jj)
      t[ty + jj * 8][tx] = src[(size_t)(k0 + ty + jj * 8) * srcN + col0 + tx];
    __syncthreads();
    for (int jj = 0; jj < 4; ++jj)
      Wqkvt[(size_t)(n0 + ty + jj * 8) * 2048 + k0 + tx] = f2b(t[tx][ty + jj * 8]);
  } else {
    if (n0 >= 2048) return;
    for (int jj = 0; jj < 4; ++jj)
      t[ty + jj * 8][tx] = Wo[(size_t)(k0 + ty + jj * 8) * 2048 + n0 + tx];
    __syncthreads();
    for (int jj = 0; jj < 4; ++jj)
      Wot[(size_t)(n0 + ty + jj * 8) * 2048 + k0 + tx] = f2b(t[tx][ty + jj * 8]);
  }
}

// ---------------- fused QKV GEMM: [4096 x 3072] = xb * Wqkvt^T ----------------
// (round-5: T1 swizzle removed — measured null/negative on these L3-resident GEMMs)
#define EPI_STRIDE 136  // shorts; 272 B rows -> 16B-aligned us8 chunks
__global__ __launch_bounds__(256) void gemm_qkv(const ushort* __restrict__ A,
                                                const ushort* __restrict__ Bt,
                                                ushort* __restrict__ qo,
                                                ushort* __restrict__ ko,
                                                ushort* __restrict__ vo,
                                                int K) {
  __shared__ alignas(16) ushort smem[128 * EPI_STRIDE];
  ushort* As = smem;          // 128*64
  ushort* Bs = smem + 8192;   // 128*64
  const int tid = threadIdx.x;
  const int lane = tid & 63;
  const int wid = tid >> 6;
  const int wm = wid >> 1, wn = wid & 1;
  const int quad = lane >> 4, l16 = lane & 15;
  const int bm = blockIdx.y * 128, bn = blockIdx.x * 128;

  fx4 acc[4][4];
  for (int i = 0; i < 4; ++i)
    for (int j = 0; j < 4; ++j) acc[i][j] = (fx4){0.f, 0.f, 0.f, 0.f};

  const int r8 = lane >> 3, s8 = lane & 7;
  for (int k0 = 0; k0 < K; k0 += 64) {
    for (int i = 0; i < 4; ++i) {
      int m = i * 32 + wid * 8 + r8;
      int c = s8 ^ (m & 7);
      gld_lds16(A + (size_t)(bm + m) * K + k0 + c * 8, As + (i * 32 + wid * 8) * 64);
      gld_lds16(Bt + (size_t)(bn + m) * K + k0 + c * 8, Bs + (i * 32 + wid * 8) * 64);
    }
    __syncthreads();
    for (int ks = 0; ks < 2; ++ks) {
      bs8 af[4], bf[4];
      for (int mt = 0; mt < 4; ++mt) {
        int m = wm * 64 + mt * 16 + l16;
        int c = ks * 4 + quad;
        int slot = c ^ (m & 7);
        af[mt] = *(const bs8*)(As + m * 64 + slot * 8);
      }
      for (int nt = 0; nt < 4; ++nt) {
        int n = wn * 64 + nt * 16 + l16;
        int c = ks * 4 + quad;
        int slot = c ^ (n & 7);
        bf[nt] = *(const bs8*)(Bs + n * 64 + slot * 8);
      }
      for (int mt = 0; mt < 4; ++mt)
        for (int nt = 0; nt < 4; ++nt)
          acc[mt][nt] = __builtin_amdgcn_mfma_f32_16x16x32_bf16(af[mt], bf[nt],
                                                                acc[mt][nt], 0, 0, 0);
    }
    __syncthreads();
  }

  // ---- epilogue: C tile -> LDS (bf16), read back row-major, 16B stores ----
  for (int mt = 0; mt < 4; ++mt)
    for (int nt = 0; nt < 4; ++nt)
      for (int r = 0; r < 4; ++r) {
        int row = wm * 64 + mt * 16 + quad * 4 + r;
        int col = wn * 64 + nt * 16 + l16;
        smem[row * EPI_STRIDE + col] = f2b(acc[mt][nt][r]);
      }
  __syncthreads();
  const int rsel = tid >> 4;   // 0..15
  const int csel = tid & 15;   // 16B chunk within row
  for (int ii = 0; ii < 8; ++ii) {
    int row = ii * 16 + rsel;
    us8 chunk = *(const us8*)(smem + row * EPI_STRIDE + csel * 8);
    int row_g = bm + row;
    int colc = bn + csel * 8;
    if (bn < 2048) {
      *(us8*)(qo + (size_t)row_g * 2048 + colc) = chunk;
    } else {
      int b = row_g >> 11, t = row_g & 2047;
      if (bn < 2560) {
        int kc = colc - 2048;
        int gg = kc >> 7, d = kc & 127;
        *(us8*)(ko + ((size_t)(b * KVH + gg) * TT + t) * HD + d) = chunk;
      } else {
        int vc = colc - 2560;
        int gg = vc >> 7, d = vc & 127;
        *(us8*)(vo + ((size_t)(b * KVH + gg) * TT + t) * HD + d) = chunk;
      }
    }
  }
}

// ---------------- transpose V: [b,g,t,d] -> [b,g,d,t] ----------------
__global__ __launch_bounds__(256) void transpose_v(const ushort* __restrict__ vin,
                                                   ushort* __restrict__ vout) {
  __shared__ ushort tl[32][33];
  int tx = threadIdx.x, ty = threadIdx.y;  // (32,8)
  int t0 = blockIdx.x * 32, d0 = blockIdx.y * 32;
  size_t base = (size_t)blockIdx.z * TT * HD;
  for (int jj = 0; jj < 4; ++jj)
    tl[ty + jj * 8][tx] = vin[base + (size_t)(t0 + ty + jj * 8) * HD + d0 + tx];
  __syncthreads();
  for (int jj = 0; jj < 4; ++jj)
    vout[base + (size_t)(d0 + ty + jj * 8) * TT + t0 + tx] = tl[tx][ty + jj * 8];
}

// ---------------- output-projection GEMM: fp32 out ----------------
__global__ __launch_bounds__(256) void gemm_out(const ushort* __restrict__ A,
                                                const ushort* __restrict__ Bt,
                                                float* __restrict__ Cout,
                                                int N, int K) {
  __shared__ alignas(16) ushort smem[128 * EPI_STRIDE];
  ushort* As = smem;
  ushort* Bs = smem + 8192;
  const int tid = threadIdx.x;
  const int lane = tid & 63;
  const int wid = tid >> 6;
  const int wm = wid >> 1, wn = wid & 1;
  const int quad = lane >> 4, l16 = lane & 15;
  const int bm = blockIdx.y * 128, bn = blockIdx.x * 128;

  fx4 acc[4][4];
  for (int i = 0; i < 4; ++i)
    for (int j = 0; j < 4; ++j) acc[i][j] = (fx4){0.f, 0.f, 0.f, 0.f};

  const int r8 = lane >> 3, s8 = lane & 7;
  for (int k0 = 0; k0 < K; k0 += 64) {
    for (int i = 0; i < 4; ++i) {
      int m = i * 32 + wid * 8 + r8;
      int c = s8 ^ (m & 7);
      gld_lds16(A + (size_t)(bm + m) * K + k0 + c * 8, As + (i * 32 + wid * 8) * 64);
      gld_lds16(Bt + (size_t)(bn + m) * K + k0 + c * 8, Bs + (i * 32 + wid * 8) * 64);
    }
    __syncthreads();
    for (int ks = 0; ks < 2; ++ks) {
      bs8 af[4], bf[4];
      for (int mt = 0; mt < 4; ++mt) {
        int m = wm * 64 + mt * 16 + l16;
        int c = ks * 4 + quad;
        int slot = c ^ (m & 7);
        af[mt] = *(const bs8*)(As + m * 64 + slot * 8);
      }
      for (int nt = 0; nt < 4; ++nt) {
        int n = wn * 64 + nt * 16 + l16;
        int c = ks * 4 + quad;
        int slot = c ^ (n & 7);
        bf[nt] = *(const bs8*)(Bs + n * 64 + slot * 8);
      }
      for (int mt = 0; mt < 4; ++mt)
        for (int nt = 0; nt < 4; ++nt)
          acc[mt][nt] = __builtin_amdgcn_mfma_f32_16x16x32_bf16(af[mt], bf[nt],
                                                                acc[mt][nt], 0, 0, 0);
    }
    __syncthreads();
  }

  // ---- epilogue: bf16 LDS round-trip, fp32 vector stores ----
  for (int mt = 0; mt < 4; ++mt)
    for (int nt = 0; nt < 4; ++nt)
      for (int r = 0; r < 4; ++r) {
        int row = wm * 64 + mt * 16 + quad * 4 + r;
        int col = wn * 64 + nt * 16 + l16;
        smem[row * EPI_STRIDE + col] = f2b(acc[mt][nt][r]);
      }
  __syncthreads();
  const int rsel = tid >> 4;
  const int csel = tid & 15;
  for (int ii = 0; ii < 8; ++ii) {
    int row = ii * 16 + rsel;
    us8 chunk = *(const us8*)(smem + row * EPI_STRIDE + csel * 8);
    int row_g = bm + row;
    int colc = bn + csel * 8;
    float4 lo = {b2f(chunk[0]), b2f(chunk[1]), b2f(chunk[2]), b2f(chunk[3])};
    float4 hi = {b2f(chunk[4]), b2f(chunk[5]), b2f(chunk[6]), b2f(chunk[7])};
    *(float4*)(Cout + (size_t)row_g * N + colc) = lo;
    *(float4*)(Cout + (size_t)row_g * N + colc + 4) = hi;
  }
}

// ---------------- fused causal WGQA attention: split-key wave pairs ----------------
// ROUND-5: 512 blocks x 512 threads (16 waves/CU preserved). 8 waves = 4 query
// groups x 2 key-halves. Wave owns 32 queries x 32 keys per 64-key tile:
//  * K-frag and V-frag LDS reads halve vs round-1 (each frag feeds 2 MFMAs via
//    nt=0,1) AT UNCHANGED WAVE COUNT — block DS traffic 288 -> 160 KB/iter.
//    (Round-2 proved the traffic cut works but lost concurrency; this keeps both.)
//  * Per-wave (m,l,o) are PARTIALS over its key-half; merged once at the end
//    through LDS overlaid on the K/V buffers (LDS stays 80 KB = 2 blocks/CU).
//  * Staging, dbuf + counted vmcnt(4), defer-max, swizzles: unchanged from r1.
__global__ __launch_bounds__(512, 4) void attn_kernel(const ushort* __restrict__ qb,
                                                      const ushort* __restrict__ kb,
                                                      const ushort* __restrict__ vt,
                                                      ushort* __restrict__ yb,
                                                      const float* __restrict__ wlog) {
  __shared__ alignas(16) ushort smem[40960];       // 80 KB exactly (2 blocks/CU)
  ushort* KsBuf = smem;                            // 2 x [64 key][128 d] swizzled
  ushort* VsBuf = smem + 16384;                    // 2 x [128 d][64 key] swizzled
  ushort* Ps = smem + 32768;                       // [128 q][64 key] swizzled

  const int bid = blockIdx.x;
  const int qt = (bid & 256) ? (bid & 15) : 15 - (bid & 15);
  const int h = (bid >> 4) & 15;
  const int b = bid >> 8;
  const int g = h >> 2;
  const int tid = threadIdx.x;
  const int lane = tid & 63;
  const int wid = tid >> 6;        // 0..7
  const int qg = wid >> 1;         // query group (32 q)
  const int kh = wid & 1;          // key half (32 keys of each 64-tile)
  const int quad = lane >> 4;
  const int l16 = lane & 15;
  const int qwv = qt * 128 + qg * 32;   // group's first query

  const float scale = wlog[g] * 0.08838834764831845f;  // 1/sqrt(128)
  const float sc2 = scale * 1.4426950408889634f;       // * log2(e)

  const ushort* kbase = kb + (size_t)(b * KVH + g) * TT * HD;
  const ushort* vbase = vt + (size_t)(b * KVH + g) * HD * TT;

  // persistent staging pointers (block-wide, independent of compute mapping)
  const ushort* kp;
  const ushort* vp;
  {
    int keyr = wid * 4 + (lane >> 4);          // 0..31
    int si = lane & 15;
    int ck = (si & 8) | ((si ^ keyr) & 7);
    kp = kbase + (size_t)keyr * HD + ck * 8;
    int dr = wid * 8 + (lane >> 3);            // 0..63
    int s8 = lane & 7;
    int cv = s8 ^ (dr & 7);
    vp = vbase + (size_t)dr * TT + cv * 8;
  }

  // ---- prologue: stage tile 0 into buffer 0 (DMA runs under Q-load) ----
  gld_lds16(kp, KsBuf + wid * 512);
  gld_lds16(kp + 32 * HD, KsBuf + 4096 + wid * 512);
  gld_lds16(vp, VsBuf + wid * 512);
  gld_lds16(vp + 64 * TT, VsBuf + 4096 + wid * 512);
  kp += 64 * HD;
  vp += 64;

  // Q fragments in registers (B-operand of S^T = K * Q^T), 2 column-blocks
  bs8 qf[2][4];
#pragma unroll
  for (int nt = 0; nt < 2; ++nt) {
    int q = qwv + nt * 16 + l16;
    const ushort* qrow = qb + ((size_t)(b * TT + q)) * DM + h * HD;
#pragma unroll
    for (int ks = 0; ks < 4; ++ks)
      qf[nt][ks] = *(const bs8*)(qrow + ks * 32 + quad * 8);
  }

  float m_i[2] = {-INFINITY, -INFINITY};  // running max of RAW logits (partial)
  float l_i[2] = {0.f, 0.f};
  fx4 o[8][2];
#pragma unroll
  for (int i = 0; i < 8; ++i)
#pragma unroll
    for (int nt = 0; nt < 2; ++nt) o[i][nt] = (fx4){0.f, 0.f, 0.f, 0.f};

  const int jmax = 2 * qt + 1;
  for (int j = 0; j <= jmax; ++j) {
    const int cur = j & 1;
    // ---- issue NEXT tile's DMAs first, then wait only for tile j ----
    if (j < jmax) {
      const int nxt = cur ^ 1;
      gld_lds16(kp, KsBuf + nxt * 8192 + wid * 512);
      gld_lds16(kp + 32 * HD, KsBuf + nxt * 8192 + 4096 + wid * 512);
      gld_lds16(vp, VsBuf + nxt * 8192 + wid * 512);
      gld_lds16(vp + 64 * TT, VsBuf + nxt * 8192 + 4096 + wid * 512);
      kp += 64 * HD;
      vp += 64;
      asm volatile("s_waitcnt vmcnt(4)" ::: "memory");  // tile j done, j+1 in flight
    } else {
      asm volatile("s_waitcnt vmcnt(0)" ::: "memory");
    }
    __builtin_amdgcn_s_barrier();

    // wave active iff its key-half has at least one unmasked key
    if (j * 64 + kh * 32 <= qwv + 31) {
      const ushort* Kc = KsBuf + cur * 8192;
      const ushort* Vc = VsBuf + cur * 8192;
      // ---- S^T = K * Q^T  (32 keys x 32 queries), fp32 acc ----
      fx4 s[2][2];
#pragma unroll
      for (int mt = 0; mt < 2; ++mt)
#pragma unroll
        for (int nt = 0; nt < 2; ++nt) s[mt][nt] = (fx4){0.f, 0.f, 0.f, 0.f};
      __builtin_amdgcn_s_setprio(1);
#pragma unroll
      for (int mt = 0; mt < 2; ++mt) {
        int key = kh * 32 + mt * 16 + l16;
        bs8 a[4];
#pragma unroll
        for (int ks = 0; ks < 4; ++ks) {
          int c = ks * 4 + quad;
          int slot = (c & 8) | ((c ^ key) & 7);
          a[ks] = *(const bs8*)(Kc + key * 128 + slot * 8);
        }
#pragma unroll
        for (int ks = 0; ks < 4; ++ks) {
          s[mt][0] = __builtin_amdgcn_mfma_f32_16x16x32_bf16(a[ks], qf[0][ks],
                                                             s[mt][0], 0, 0, 0);
          s[mt][1] = __builtin_amdgcn_mfma_f32_16x16x32_bf16(a[ks], qf[1][ks],
                                                             s[mt][1], 0, 0, 0);
        }
      }
      __builtin_amdgcn_s_setprio(0);

      // ---- causal mask: needed iff this wave's key-half straddles the diagonal ----
      if (j * 64 + kh * 32 + 31 > qwv) {
#pragma unroll
        for (int nt = 0; nt < 2; ++nt) {
          int q = qwv + nt * 16 + l16;
#pragma unroll
          for (int mt = 0; mt < 2; ++mt)
#pragma unroll
            for (int r = 0; r < 4; ++r) {
              int key = j * 64 + kh * 32 + mt * 16 + quad * 4 + r;
              if (key > q) s[mt][nt][r] = -1e30f;
            }
        }
      }
      float mx[2];
#pragma unroll
      for (int nt = 0; nt < 2; ++nt) {
        float m = s[0][nt][0];
#pragma unroll
        for (int mt = 0; mt < 2; ++mt)
#pragma unroll
          for (int r = 0; r < 4; ++r) m = fmaxf(m, s[mt][nt][r]);
        m = fmaxf(m, __shfl_xor(m, 16));
        m = fmaxf(m, __shfl_xor(m, 32));
        mx[nt] = m;
      }

      // ---- defer-max: only rescale when a max actually grows (>8 scaled) ----
      bool ok = ((mx[0] - m_i[0]) * scale <= 8.0f) &&
                ((mx[1] - m_i[1]) * scale <= 8.0f);
      if (!__all(ok)) {
#pragma unroll
        for (int nt = 0; nt < 2; ++nt) {
          float m_new = fmaxf(m_i[nt], mx[nt]);
          float alpha = EXP2((m_i[nt] - m_new) * sc2);
          l_i[nt] *= alpha;
#pragma unroll
          for (int dmt = 0; dmt < 8; ++dmt)
#pragma unroll
            for (int r = 0; r < 4; ++r) o[dmt][nt][r] *= alpha;
          m_i[nt] = m_new;
        }
      }
#pragma unroll
      for (int nt = 0; nt < 2; ++nt) {
        float negb = -m_i[nt] * sc2;
        float sum = 0.f;
#pragma unroll
        for (int mt = 0; mt < 2; ++mt)
#pragma unroll
          for (int r = 0; r < 4; ++r) {
            float pv = EXP2(fmaf(s[mt][nt][r], sc2, negb));
            s[mt][nt][r] = pv;
            sum += pv;
          }
        sum += __shfl_xor(sum, 16);
        sum += __shfl_xor(sum, 32);
        l_i[nt] += sum;
      }

      // P (bf16) to LDS; wave writes only its own 32 rows x its key-half columns
      const int sw = l16 & 7;
#pragma unroll
      for (int nt = 0; nt < 2; ++nt) {
        int qrow = qg * 32 + nt * 16 + l16;
#pragma unroll
        for (int mt = 0; mt < 2; ++mt) {
          us4 pw = {f2b(s[mt][nt][0]), f2b(s[mt][nt][1]),
                    f2b(s[mt][nt][2]), f2b(s[mt][nt][3])};
          int chunk = kh * 4 + mt * 2 + (quad >> 1);
          *(us4*)(Ps + qrow * 64 + ((chunk ^ sw) << 3) + ((quad & 1) << 2)) = pw;
        }
      }

      // ---- O^T += V^T[:, key-half] * P^T  (k=32 per MFMA = wave's key-half) ----
      {
        int qrow0 = qg * 32 + l16;
        int c = kh * 4 + quad;
        bs8 pb0 = *(const bs8*)(Ps + qrow0 * 64 + ((c ^ sw) << 3));
        bs8 pb1 = *(const bs8*)(Ps + (qrow0 + 16) * 64 + ((c ^ sw) << 3));
        __builtin_amdgcn_s_setprio(1);
#pragma unroll
        for (int dmt = 0; dmt < 8; ++dmt) {
          int d = dmt * 16 + l16;
          int slot = c ^ (d & 7);
          bs8 va = *(const bs8*)(Vc + d * 64 + slot * 8);
          o[dmt][0] = __builtin_amdgcn_mfma_f32_16x16x32_bf16(va, pb0, o[dmt][0], 0, 0, 0);
          o[dmt][1] = __builtin_amdgcn_mfma_f32_16x16x32_bf16(va, pb1, o[dmt][1], 0, 0, 0);
        }
        __builtin_amdgcn_s_setprio(0);
      }
    }
    // all my LDS reads of buf[cur] must be complete before signaling
    asm volatile("s_waitcnt lgkmcnt(0)" ::: "memory");
    __builtin_amdgcn_s_barrier();
  }

  // ---- merge key-half partials (kh=1 -> LDS overlay on K/V buffers) ----
  float* Ex = (float*)smem;              // [qg][32 q][stride 132] fp32
  float* Ml = Ex + 4 * 32 * 132;         // [qg][nt][m:0..15 | l:16..31]
  if (kh == 1) {
#pragma unroll
    for (int nt = 0; nt < 2; ++nt) {
      float* exq = Ex + qg * 4224 + (nt * 16 + l16) * 132 + quad * 4;
#pragma unroll
      for (int dmt = 0; dmt < 8; ++dmt)
        *(fx4*)(exq + dmt * 16) = o[dmt][nt];
      if (quad == 0) {
        Ml[qg * 64 + nt * 32 + l16] = m_i[nt];
        Ml[qg * 64 + nt * 32 + 16 + l16] = l_i[nt];
      }
    }
  }
  __syncthreads();
  if (kh == 0) {
#pragma unroll
    for (int nt = 0; nt < 2; ++nt) {
      float m1 = Ml[qg * 64 + nt * 32 + l16];
      float l1 = Ml[qg * 64 + nt * 32 + 16 + l16];
      float m = fmaxf(m_i[nt], m1);
      float a0 = EXP2((m_i[nt] - m) * sc2);
      float a1 = EXP2((m1 - m) * sc2);
      float inv = 1.0f / (l_i[nt] * a0 + l1 * a1);
      float w0 = a0 * inv, w1 = a1 * inv;
      int q = qwv + nt * 16 + l16;
      ushort* yrow = yb + ((size_t)(b * TT + q)) * DM + h * HD;
      const float* exq = Ex + qg * 4224 + (nt * 16 + l16) * 132 + quad * 4;
#pragma unroll
      for (int dmt = 0; dmt < 8; ++dmt) {
        fx4 o1 = *(const fx4*)(exq + dmt * 16);
        us4 w = {f2b(o[dmt][nt][0] * w0 + o1[0] * w1),
                 f2b(o[dmt][nt][1] * w0 + o1[1] * w1),
                 f2b(o[dmt][nt][2] * w0 + o1[2] * w1),
                 f2b(o[dmt][nt][3] * w0 + o1[3] * w1)};
        *(us4*)(yrow + dmt * 16 + quad * 4) = w;
      }
    }
  }
}

// ---------------- launch ----------------
extern "C" void kernel_launch(void* const* d_in, const int* in_sizes, int n_in,
                              void* d_out, int out_size, void* d_ws, size_t ws_size,
                              hipStream_t stream) {
  const float* x = (const float*)d_in[0];
  // d_in[1] = attn_mask: ignored (exact causal mask computed analytically)
  const float* Wq = (const float*)d_in[2];
  const float* Wk = (const float*)d_in[3];
  const float* Wv = (const float*)d_in[4];
  const float* Wo = (const float*)d_in[5];
  const float* wlog = (const float*)d_in[6];
  // d_in[7] = weight_values: unused by the reference

  char* ws = (char*)d_ws;
  ushort* xb = (ushort*)ws;     ws += (size_t)4096 * 2048 * 2;
  ushort* Wqkvt = (ushort*)ws;  ws += (size_t)3072 * 2048 * 2;
  ushort* Wot = (ushort*)ws;    ws += (size_t)2048 * 2048 * 2;
  ushort* qbuf = (ushort*)ws;   ws += (size_t)4096 * 2048 * 2;
  ushort* kbuf = (ushort*)ws;   ws += (size_t)2 * KVH * 2048 * 128 * 2;
  ushort* vtmp = (ushort*)ws;   ws += (size_t)2 * KVH * 2048 * 128 * 2;
  ushort* vbuf = (ushort*)ws;   ws += (size_t)2 * KVH * 2048 * 128 * 2;
  ushort* ybuf = (ushort*)ws;   ws += (size_t)4096 * 2048 * 2;

  prep_kernel<<<dim3(96, 64, 3), dim3(32, 8), 0, stream>>>(
      x, Wq, Wk, Wv, Wo, xb, Wqkvt, Wot);
  gemm_qkv<<<dim3(24, 32), 256, 0, stream>>>(xb, Wqkvt, qbuf, kbuf, vtmp, 2048);
  transpose_v<<<dim3(64, 4, 8), dim3(32, 8), 0, stream>>>(vtmp, vbuf);
  attn_kernel<<<512, 512, 0, stream>>>(qbuf, kbuf, vbuf, ybuf, wlog);
  gemm_out<<<dim3(16, 32), 256, 0, stream>>>(ybuf, Wot, (float*)d_out, 2048, 2048);
}

// Round 7
// 318.651 us; speedup vs baseline: 1.3369x; 1.3369x over previous
//
#include <hip/hip_runtime.h>
#include <hip/hip_bf16.h>

#define TT 2048
#define DM 2048
#define NH 16
#define KVH 4
#define HD 128

typedef __attribute__((ext_vector_type(8))) short bs8;
typedef __attribute__((ext_vector_type(4))) float fx4;
typedef __attribute__((ext_vector_type(4))) unsigned short us4;
typedef __attribute__((ext_vector_type(8))) unsigned short us8;

#if __has_builtin(__builtin_amdgcn_exp2f)
#define EXP2(x) __builtin_amdgcn_exp2f(x)
#else
#define EXP2(x) exp2f(x)
#endif

__device__ inline unsigned short f2b(float f) {
  __hip_bfloat16 h = __float2bfloat16(f);
  return *reinterpret_cast<unsigned short*>(&h);
}

__device__ inline float b2f(unsigned short u) {
  unsigned int v = ((unsigned int)u) << 16;
  return *reinterpret_cast<float*>(&v);
}

__device__ inline void gld_lds16(const ushort* g, ushort* l) {
  __builtin_amdgcn_global_load_lds(
      (const __attribute__((address_space(1))) void*)g,
      (__attribute__((address_space(3))) void*)l,
      16, 0, 0);
}

// ---------------- prep: weight transposes + x cast, one dispatch ----------------
// z=0: Wqkvt[3072][2048] from Wq|Wk|Wv   z=1: Wot[2048][2048] from Wo
// z=2: x fp32 -> bf16 cast (linear)
__global__ __launch_bounds__(256) void prep_kernel(
    const float* __restrict__ x, const float* __restrict__ Wq,
    const float* __restrict__ Wk, const float* __restrict__ Wv,
    const float* __restrict__ Wo, ushort* __restrict__ xb,
    ushort* __restrict__ Wqkvt, ushort* __restrict__ Wot) {
  int tx = threadIdx.x, ty = threadIdx.y;  // block (32,8)
  if (blockIdx.z == 2) {
    int lin = (blockIdx.y * 96 + blockIdx.x) * 256 + ty * 32 + tx;
#pragma unroll
    for (int it = 0; it < 2; ++it) {
      int i = lin + it * (6144 * 256);
      if (i < (TT * 2 * DM) / 4) {
        float4 v = ((const float4*)x)[i];
        us4 o = {f2b(v.x), f2b(v.y), f2b(v.z), f2b(v.w)};
        ((us4*)xb)[i] = o;
      }
    }
    return;
  }
  __shared__ float t[32][33];
  int n0 = blockIdx.x * 32, k0 = blockIdx.y * 32;
  if (blockIdx.z == 0) {
    const float* src;
    int srcN, col0;
    if (n0 < 2048) { src = Wq; srcN = 2048; col0 = n0; }
    else if (n0 < 2560) { src = Wk; srcN = 512; col0 = n0 - 2048; }
    else { src = Wv; srcN = 512; col0 = n0 - 2560; }
    for (int jj = 0; jj < 4; ++jj)
      t[ty + jj * 8][tx] = src[(size_t)(k0 + ty + jj * 8) * srcN + col0 + tx];
    __syncthreads();
    for (int jj = 0; jj < 4; ++jj)
      Wqkvt[(size_t)(n0 + ty + jj * 8) * 2048 + k0 + tx] = f2b(t[tx][ty + jj * 8]);
  } else {
    if (n0 >= 2048) return;
    for (int jj = 0; jj < 4; ++jj)
      t[ty + jj * 8][tx] = Wo[(size_t)(k0 + ty + jj * 8) * 2048 + n0 + tx];
    __syncthreads();
    for (int jj = 0; jj < 4; ++jj)
      Wot[(size_t)(n0 + ty + jj * 8) * 2048 + k0 + tx] = f2b(t[tx][ty + jj * 8]);
  }
}

// ---------------- fused QKV GEMM: [4096 x 3072] = xb * Wqkvt^T ----------------
// Epilogue writes: q rowmajor, k [b,g,t,d], v TRANSPOSED [b,g,d,t] directly
// (transpose_v kernel fused here — column reads from the epilogue LDS
//  with jj-rotation so the 16-lane column read spreads across 8 banks).
#define EPI_STRIDE 136  // shorts; 272 B rows -> 16B-aligned us8 chunks
__global__ __launch_bounds__(256) void gemm_qkv(const ushort* __restrict__ A,
                                                const ushort* __restrict__ Bt,
                                                ushort* __restrict__ qo,
                                                ushort* __restrict__ ko,
                                                ushort* __restrict__ vo,
                                                int K) {
  __shared__ alignas(16) ushort smem[128 * EPI_STRIDE];
  ushort* As = smem;          // 128*64
  ushort* Bs = smem + 8192;   // 128*64
  const int tid = threadIdx.x;
  const int lane = tid & 63;
  const int wid = tid >> 6;
  const int wm = wid >> 1, wn = wid & 1;
  const int quad = lane >> 4, l16 = lane & 15;
  const int bm = blockIdx.y * 128, bn = blockIdx.x * 128;

  fx4 acc[4][4];
  for (int i = 0; i < 4; ++i)
    for (int j = 0; j < 4; ++j) acc[i][j] = (fx4){0.f, 0.f, 0.f, 0.f};

  const int r8 = lane >> 3, s8 = lane & 7;
  for (int k0 = 0; k0 < K; k0 += 64) {
    for (int i = 0; i < 4; ++i) {
      int m = i * 32 + wid * 8 + r8;
      int c = s8 ^ (m & 7);
      gld_lds16(A + (size_t)(bm + m) * K + k0 + c * 8, As + (i * 32 + wid * 8) * 64);
      gld_lds16(Bt + (size_t)(bn + m) * K + k0 + c * 8, Bs + (i * 32 + wid * 8) * 64);
    }
    __syncthreads();
    for (int ks = 0; ks < 2; ++ks) {
      bs8 af[4], bf[4];
      for (int mt = 0; mt < 4; ++mt) {
        int m = wm * 64 + mt * 16 + l16;
        int c = ks * 4 + quad;
        int slot = c ^ (m & 7);
        af[mt] = *(const bs8*)(As + m * 64 + slot * 8);
      }
      for (int nt = 0; nt < 4; ++nt) {
        int n = wn * 64 + nt * 16 + l16;
        int c = ks * 4 + quad;
        int slot = c ^ (n & 7);
        bf[nt] = *(const bs8*)(Bs + n * 64 + slot * 8);
      }
      for (int mt = 0; mt < 4; ++mt)
        for (int nt = 0; nt < 4; ++nt)
          acc[mt][nt] = __builtin_amdgcn_mfma_f32_16x16x32_bf16(af[mt], bf[nt],
                                                                acc[mt][nt], 0, 0, 0);
    }
    __syncthreads();
  }

  // ---- epilogue: C tile -> LDS (bf16), read back, 16B stores ----
  for (int mt = 0; mt < 4; ++mt)
    for (int nt = 0; nt < 4; ++nt)
      for (int r = 0; r < 4; ++r) {
        int row = wm * 64 + mt * 16 + quad * 4 + r;
        int col = wn * 64 + nt * 16 + l16;
        smem[row * EPI_STRIDE + col] = f2b(acc[mt][nt][r]);
      }
  __syncthreads();
  if (bn < 2560) {
    // q / k paths: row-major us8 reads, direct stores
    const int rsel = tid >> 4;   // 0..15
    const int csel = tid & 15;   // 16B chunk within row
    for (int ii = 0; ii < 8; ++ii) {
      int row = ii * 16 + rsel;
      us8 chunk = *(const us8*)(smem + row * EPI_STRIDE + csel * 8);
      int row_g = bm + row;
      int colc = bn + csel * 8;
      if (bn < 2048) {
        *(us8*)(qo + (size_t)row_g * 2048 + colc) = chunk;
      } else {
        int b = row_g >> 11, t = row_g & 2047;
        int kc = colc - 2048;
        int gg = kc >> 7, d = kc & 127;
        *(us8*)(ko + ((size_t)(b * KVH + gg) * TT + t) * HD + d) = chunk;
      }
    }
  } else {
    // V path: transposed store [b,g,d,t] straight from LDS column reads.
    // tile = [token 0..127][d 0..127] for one (b,gg); us8 runs along t.
    const int gg = (bn - 2560) >> 7;
    const int b = bm >> 11;        // 128-row tile never straddles b (2048%128==0)
    const int t0 = bm & 2047;
    const int tc = tid & 15;       // t-chunk (8 tokens)
    const int drow = tid >> 4;     // 0..15
    for (int it = 0; it < 8; ++it) {
      int d = it * 16 + drow;
      us8 pw;
#pragma unroll
      for (int j = 0; j < 8; ++j) {
        int jj = (j + tc) & 7;     // rotate: column read spreads over 8 banks
        pw[jj] = smem[(tc * 8 + jj) * EPI_STRIDE + d];
      }
      *(us8*)(vo + ((size_t)(b * KVH + gg) * HD + d) * TT + t0 + tc * 8) = pw;
    }
  }
}

// ---------------- output-projection GEMM: fp32 out ----------------
__global__ __launch_bounds__(256) void gemm_out(const ushort* __restrict__ A,
                                                const ushort* __restrict__ Bt,
                                                float* __restrict__ Cout,
                                                int N, int K) {
  __shared__ alignas(16) ushort smem[128 * EPI_STRIDE];
  ushort* As = smem;
  ushort* Bs = smem + 8192;
  const int tid = threadIdx.x;
  const int lane = tid & 63;
  const int wid = tid >> 6;
  const int wm = wid >> 1, wn = wid & 1;
  const int quad = lane >> 4, l16 = lane & 15;
  const int bm = blockIdx.y * 128, bn = blockIdx.x * 128;

  fx4 acc[4][4];
  for (int i = 0; i < 4; ++i)
    for (int j = 0; j < 4; ++j) acc[i][j] = (fx4){0.f, 0.f, 0.f, 0.f};

  const int r8 = lane >> 3, s8 = lane & 7;
  for (int k0 = 0; k0 < K; k0 += 64) {
    for (int i = 0; i < 4; ++i) {
      int m = i * 32 + wid * 8 + r8;
      int c = s8 ^ (m & 7);
      gld_lds16(A + (size_t)(bm + m) * K + k0 + c * 8, As + (i * 32 + wid * 8) * 64);
      gld_lds16(Bt + (size_t)(bn + m) * K + k0 + c * 8, Bs + (i * 32 + wid * 8) * 64);
    }
    __syncthreads();
    for (int ks = 0; ks < 2; ++ks) {
      bs8 af[4], bf[4];
      for (int mt = 0; mt < 4; ++mt) {
        int m = wm * 64 + mt * 16 + l16;
        int c = ks * 4 + quad;
        int slot = c ^ (m & 7);
        af[mt] = *(const bs8*)(As + m * 64 + slot * 8);
      }
      for (int nt = 0; nt < 4; ++nt) {
        int n = wn * 64 + nt * 16 + l16;
        int c = ks * 4 + quad;
        int slot = c ^ (n & 7);
        bf[nt] = *(const bs8*)(Bs + n * 64 + slot * 8);
      }
      for (int mt = 0; mt < 4; ++mt)
        for (int nt = 0; nt < 4; ++nt)
          acc[mt][nt] = __builtin_amdgcn_mfma_f32_16x16x32_bf16(af[mt], bf[nt],
                                                                acc[mt][nt], 0, 0, 0);
    }
    __syncthreads();
  }

  // ---- epilogue: bf16 LDS round-trip, fp32 vector stores ----
  for (int mt = 0; mt < 4; ++mt)
    for (int nt = 0; nt < 4; ++nt)
      for (int r = 0; r < 4; ++r) {
        int row = wm * 64 + mt * 16 + quad * 4 + r;
        int col = wn * 64 + nt * 16 + l16;
        smem[row * EPI_STRIDE + col] = f2b(acc[mt][nt][r]);
      }
  __syncthreads();
  const int rsel = tid >> 4;
  const int csel = tid & 15;
  for (int ii = 0; ii < 8; ++ii) {
    int row = ii * 16 + rsel;
    us8 chunk = *(const us8*)(smem + row * EPI_STRIDE + csel * 8);
    int row_g = bm + row;
    int colc = bn + csel * 8;
    float4 lo = {b2f(chunk[0]), b2f(chunk[1]), b2f(chunk[2]), b2f(chunk[3])};
    float4 hi = {b2f(chunk[4]), b2f(chunk[5]), b2f(chunk[6]), b2f(chunk[7])};
    *(float4*)(Cout + (size_t)row_g * N + colc) = lo;
    *(float4*)(Cout + (size_t)row_g * N + colc + 4) = hi;
  }
}

// ---------------- fused causal WGQA attention, 8-wave blocks ----------------
// Verbatim proven 71.5 us version (round-1/round-4).
// 512 blocks x 512 threads. Block = 128-query chunk; wave owns 16 queries.
//  * K/V double-buffered LDS, tile j+1 DMAs issued before counted vmcnt(4).
//  * defer-max (T13), exp2 folding, chunk-XOR swizzles, setprio around MFMA.
//  * complementary qt pairing keeps per-CU iteration count uniform (34).
// Ledger: 32q/wave (r2) -> concurrency-bound; V-from-L2 (r3) -> latency-bound;
// split-key partials (r5) -> VGPR spill. This structure is the local optimum.
__global__ __launch_bounds__(512, 4) void attn_kernel(const ushort* __restrict__ qb,
                                                      const ushort* __restrict__ kb,
                                                      const ushort* __restrict__ vt,
                                                      ushort* __restrict__ yb,
                                                      const float* __restrict__ wlog) {
  __shared__ alignas(16) ushort Ks[2][64 * 128];   // [buf][key][d], chunk-swizzled
  __shared__ alignas(16) ushort Vs[2][128 * 64];   // [buf][d][key], chunk-swizzled
  __shared__ alignas(16) ushort Ps[128 * 64];      // [q][key], chunk-XOR swizzled

  const int bid = blockIdx.x;
  const int qt = (bid & 256) ? (bid & 15) : 15 - (bid & 15);
  const int h = (bid >> 4) & 15;
  const int b = bid >> 8;
  const int g = h >> 2;
  const int tid = threadIdx.x;
  const int lane = tid & 63;
  const int wid = tid >> 6;        // 0..7
  const int quad = lane >> 4;
  const int l16 = lane & 15;
  const int qw = qt * 128 + wid * 16;   // wave's first query

  const float scale = wlog[g] * 0.08838834764831845f;  // 1/sqrt(128)
  const float sc2 = scale * 1.4426950408889634f;       // * log2(e)

  const ushort* kbase = kb + (size_t)(b * KVH + g) * TT * HD;
  const ushort* vbase = vt + (size_t)(b * KVH + g) * HD * TT;

  // persistent staging pointers; each thread stages 2 K-slots + 2 V-slots
  const ushort* kp;
  const ushort* vp;
  {
    int keyr = wid * 4 + (lane >> 4);          // 0..31
    int si = lane & 15;
    int ck = (si & 8) | ((si ^ keyr) & 7);
    kp = kbase + (size_t)keyr * HD + ck * 8;
    int dr = wid * 8 + (lane >> 3);            // 0..63
    int s8 = lane & 7;
    int cv = s8 ^ (dr & 7);
    vp = vbase + (size_t)dr * TT + cv * 8;
  }

  // ---- prologue: stage tile 0 into buffer 0 (DMA runs under Q-load) ----
  gld_lds16(kp, &Ks[0][wid * 512]);
  gld_lds16(kp + 32 * HD, &Ks[0][4096 + wid * 512]);
  gld_lds16(vp, &Vs[0][wid * 512]);
  gld_lds16(vp + 64 * TT, &Vs[0][4096 + wid * 512]);
  kp += 64 * HD;
  vp += 64;

  // Q fragments in registers (B-operand of S^T = K * Q^T)
  bs8 qf[4];
  {
    int q = qw + l16;
    const ushort* qrow = qb + ((size_t)(b * TT + q)) * DM + h * HD;
#pragma unroll
    for (int ks = 0; ks < 4; ++ks)
      qf[ks] = *(const bs8*)(qrow + ks * 32 + quad * 8);
  }

  float m_i = -INFINITY;  // running max of RAW logits
  float l_i = 0.f;
  fx4 o[8];
#pragma unroll
  for (int i = 0; i < 8; ++i) o[i] = (fx4){0.f, 0.f, 0.f, 0.f};

  const int jmax = 2 * qt + 1;
  for (int j = 0; j <= jmax; ++j) {
    const int cur = j & 1;
    // ---- issue NEXT tile's DMAs first, then wait only for tile j ----
    if (j < jmax) {
      const int nxt = cur ^ 1;
      gld_lds16(kp, &Ks[nxt][wid * 512]);
      gld_lds16(kp + 32 * HD, &Ks[nxt][4096 + wid * 512]);
      gld_lds16(vp, &Vs[nxt][wid * 512]);
      gld_lds16(vp + 64 * TT, &Vs[nxt][4096 + wid * 512]);
      kp += 64 * HD;
      vp += 64;
      asm volatile("s_waitcnt vmcnt(4)" ::: "memory");  // tile j done, j+1 in flight
    } else {
      asm volatile("s_waitcnt vmcnt(0)" ::: "memory");
    }
    __builtin_amdgcn_s_barrier();

    if (j * 64 <= qw + 15) {  // wave has at least one unmasked key
      const ushort* Kc = Ks[cur];
      const ushort* Vc = Vs[cur];
      // ---- S^T = K * Q^T  (64 keys x 16 queries), fp32 acc ----
      fx4 s[4];
#pragma unroll
      for (int mt = 0; mt < 4; ++mt) s[mt] = (fx4){0.f, 0.f, 0.f, 0.f};
      __builtin_amdgcn_s_setprio(1);
#pragma unroll
      for (int mt = 0; mt < 4; ++mt) {
        bs8 a[4];
        int key = mt * 16 + l16;
#pragma unroll
        for (int ks = 0; ks < 4; ++ks) {
          int c = ks * 4 + quad;
          int slot = (c & 8) | ((c ^ key) & 7);
          a[ks] = *(const bs8*)(Kc + key * 128 + slot * 8);
        }
#pragma unroll
        for (int ks = 0; ks < 4; ++ks)
          s[mt] = __builtin_amdgcn_mfma_f32_16x16x32_bf16(a[ks], qf[ks],
                                                          s[mt], 0, 0, 0);
      }
      __builtin_amdgcn_s_setprio(0);

      // ---- causal mask: needed iff tile max key > wave min query ----
      const int q = qw + l16;
      if (j * 64 + 63 > qw) {
#pragma unroll
        for (int mt = 0; mt < 4; ++mt)
#pragma unroll
          for (int r = 0; r < 4; ++r) {
            int key = j * 64 + mt * 16 + quad * 4 + r;
            if (key > q) s[mt][r] = -1e30f;
          }
      }
      float mx = s[0][0];
#pragma unroll
      for (int mt = 0; mt < 4; ++mt)
#pragma unroll
        for (int r = 0; r < 4; ++r) mx = fmaxf(mx, s[mt][r]);
      mx = fmaxf(mx, __shfl_xor(mx, 16));
      mx = fmaxf(mx, __shfl_xor(mx, 32));

      // ---- defer-max: only rescale when the max actually grows (>8 scaled) ----
      if (!__all((mx - m_i) * scale <= 8.0f)) {
        float m_new = fmaxf(m_i, mx);
        float alpha = EXP2((m_i - m_new) * sc2);
        l_i *= alpha;
#pragma unroll
        for (int dmt = 0; dmt < 8; ++dmt)
#pragma unroll
          for (int r = 0; r < 4; ++r) o[dmt][r] *= alpha;
        m_i = m_new;
      }
      float negb = -m_i * sc2;
      float sum = 0.f;
#pragma unroll
      for (int mt = 0; mt < 4; ++mt)
#pragma unroll
        for (int r = 0; r < 4; ++r) {
          float pv = EXP2(fmaf(s[mt][r], sc2, negb));
          s[mt][r] = pv;
          sum += pv;
        }
      sum += __shfl_xor(sum, 16);
      sum += __shfl_xor(sum, 32);
      l_i += sum;

      // P (bf16) to LDS, [q][key] stride 64 with chunk-XOR swizzle;
      // wave touches only its own 16 rows -> no barrier needed
      int qrow = wid * 16 + l16;
      int sw = l16 & 7;
#pragma unroll
      for (int mt = 0; mt < 4; ++mt) {
        us4 pw = {f2b(s[mt][0]), f2b(s[mt][1]), f2b(s[mt][2]), f2b(s[mt][3])};
        int chunk = mt * 2 + (quad >> 1);
        *(us4*)(Ps + qrow * 64 + ((chunk ^ sw) << 3) + ((quad & 1) << 2)) = pw;
      }

      // ---- O^T += V^T * P^T  (no barrier: wave reads only its own P rows) ----
#pragma unroll
      for (int ks = 0; ks < 2; ++ks) {
        bs8 pb = *(const bs8*)(Ps + qrow * 64 + (((ks * 4 + quad) ^ sw) << 3));
        __builtin_amdgcn_s_setprio(1);
#pragma unroll
        for (int dmt = 0; dmt < 8; ++dmt) {
          int d = dmt * 16 + l16;
          int c = ks * 4 + quad;
          int slot = c ^ (d & 7);
          bs8 va = *(const bs8*)(Vc + d * 64 + slot * 8);
          o[dmt] = __builtin_amdgcn_mfma_f32_16x16x32_bf16(va, pb, o[dmt], 0, 0, 0);
        }
        __builtin_amdgcn_s_setprio(0);
      }
    }
    // all my LDS reads of buf[cur] must be complete before signaling; the
    // barrier then licenses other waves' DMAs for tile j+2 to overwrite it
    asm volatile("s_waitcnt lgkmcnt(0)" ::: "memory");
    __builtin_amdgcn_s_barrier();
  }

  // ---- epilogue: normalize and write y (bf16, [b][t][h*128+d]) ----
  {
    float inv = 1.0f / l_i;
    int q = qw + l16;
    ushort* yrow = yb + ((size_t)(b * TT + q)) * DM + h * HD;
#pragma unroll
    for (int dmt = 0; dmt < 8; ++dmt) {
      us4 w = {f2b(o[dmt][0] * inv), f2b(o[dmt][1] * inv),
               f2b(o[dmt][2] * inv), f2b(o[dmt][3] * inv)};
      *(us4*)(yrow + dmt * 16 + quad * 4) = w;
    }
  }
}

// ---------------- launch ----------------
extern "C" void kernel_launch(void* const* d_in, const int* in_sizes, int n_in,
                              void* d_out, int out_size, void* d_ws, size_t ws_size,
                              hipStream_t stream) {
  const float* x = (const float*)d_in[0];
  // d_in[1] = attn_mask: ignored (exact causal mask computed analytically)
  const float* Wq = (const float*)d_in[2];
  const float* Wk = (const float*)d_in[3];
  const float* Wv = (const float*)d_in[4];
  const float* Wo = (const float*)d_in[5];
  const float* wlog = (const float*)d_in[6];
  // d_in[7] = weight_values: unused by the reference

  char* ws = (char*)d_ws;
  ushort* xb = (ushort*)ws;     ws += (size_t)4096 * 2048 * 2;
  ushort* Wqkvt = (ushort*)ws;  ws += (size_t)3072 * 2048 * 2;
  ushort* Wot = (ushort*)ws;    ws += (size_t)2048 * 2048 * 2;
  ushort* qbuf = (ushort*)ws;   ws += (size_t)4096 * 2048 * 2;
  ushort* kbuf = (ushort*)ws;   ws += (size_t)2 * KVH * 2048 * 128 * 2;
  ushort* vbuf = (ushort*)ws;   ws += (size_t)2 * KVH * 2048 * 128 * 2;
  ushort* ybuf = (ushort*)ws;   ws += (size_t)4096 * 2048 * 2;

  prep_kernel<<<dim3(96, 64, 3), dim3(32, 8), 0, stream>>>(
      x, Wq, Wk, Wv, Wo, xb, Wqkvt, Wot);
  gemm_qkv<<<dim3(24, 32), 256, 0, stream>>>(xb, Wqkvt, qbuf, kbuf, vbuf, 2048);
  attn_kernel<<<512, 512, 0, stream>>>(qbuf, kbuf, vbuf, ybuf, wlog);
  gemm_out<<<dim3(16, 32), 256, 0, stream>>>(ybuf, Wot, (float*)d_out, 2048, 2048);
}

// Round 8
// 307.311 us; speedup vs baseline: 1.3862x; 1.0369x over previous
//
#include <hip/hip_runtime.h>
#include <hip/hip_bf16.h>

#define TT 2048
#define DM 2048
#define NH 16
#define KVH 4
#define HD 128

typedef __attribute__((ext_vector_type(8))) short bs8;
typedef __attribute__((ext_vector_type(4))) float fx4;
typedef __attribute__((ext_vector_type(4))) unsigned short us4;
typedef __attribute__((ext_vector_type(8))) unsigned short us8;

#if __has_builtin(__builtin_amdgcn_exp2f)
#define EXP2(x) __builtin_amdgcn_exp2f(x)
#else
#define EXP2(x) exp2f(x)
#endif

__device__ inline unsigned short f2b(float f) {
  __hip_bfloat16 h = __float2bfloat16(f);
  return *reinterpret_cast<unsigned short*>(&h);
}

__device__ inline float b2f(unsigned short u) {
  unsigned int v = ((unsigned int)u) << 16;
  return *reinterpret_cast<float*>(&v);
}

__device__ inline void gld_lds16(const ushort* g, ushort* l) {
  __builtin_amdgcn_global_load_lds(
      (const __attribute__((address_space(1))) void*)g,
      (__attribute__((address_space(3))) void*)l,
      16, 0, 0);
}

// ---------------- prep: weight transposes + x cast, one dispatch ----------------
// z=0: Wqkvt[3072][2048] from Wq|Wk|Wv   z=1: Wot[2048][2048] from Wo
// z=2: x fp32 -> bf16 cast (linear)
__global__ __launch_bounds__(256) void prep_kernel(
    const float* __restrict__ x, const float* __restrict__ Wq,
    const float* __restrict__ Wk, const float* __restrict__ Wv,
    const float* __restrict__ Wo, ushort* __restrict__ xb,
    ushort* __restrict__ Wqkvt, ushort* __restrict__ Wot) {
  int tx = threadIdx.x, ty = threadIdx.y;  // block (32,8)
  if (blockIdx.z == 2) {
    int lin = (blockIdx.y * 96 + blockIdx.x) * 256 + ty * 32 + tx;
#pragma unroll
    for (int it = 0; it < 2; ++it) {
      int i = lin + it * (6144 * 256);
      if (i < (TT * 2 * DM) / 4) {
        float4 v = ((const float4*)x)[i];
        us4 o = {f2b(v.x), f2b(v.y), f2b(v.z), f2b(v.w)};
        ((us4*)xb)[i] = o;
      }
    }
    return;
  }
  __shared__ float t[32][33];
  int n0 = blockIdx.x * 32, k0 = blockIdx.y * 32;
  if (blockIdx.z == 0) {
    const float* src;
    int srcN, col0;
    if (n0 < 2048) { src = Wq; srcN = 2048; col0 = n0; }
    else if (n0 < 2560) { src = Wk; srcN = 512; col0 = n0 - 2048; }
    else { src = Wv; srcN = 512; col0 = n0 - 2560; }
    for (int jj = 0; jj < 4; ++jj)
      t[ty + jj * 8][tx] = src[(size_t)(k0 + ty + jj * 8) * srcN + col0 + tx];
    __syncthreads();
    for (int jj = 0; jj < 4; ++jj)
      Wqkvt[(size_t)(n0 + ty + jj * 8) * 2048 + k0 + tx] = f2b(t[tx][ty + jj * 8]);
  } else {
    if (n0 >= 2048) return;
    for (int jj = 0; jj < 4; ++jj)
      t[ty + jj * 8][tx] = Wo[(size_t)(k0 + ty + jj * 8) * 2048 + n0 + tx];
    __syncthreads();
    for (int jj = 0; jj < 4; ++jj)
      Wot[(size_t)(n0 + ty + jj * 8) * 2048 + k0 + tx] = f2b(t[tx][ty + jj * 8]);
  }
}

// ---------------- fused QKV GEMM: [4096 x 3072] = xb * Wqkvt^T ----------------
// Epilogue writes: q rowmajor, k [b,g,t,d], v TRANSPOSED [b,g,d,t] directly.
// ROUND-8: V path rewritten — round-7's pw[jj] runtime vector index sent pw to
// scratch (rule #20: 64 scratch stores/thread -> HBM traffic). Now V blocks
// store acc DIRECTLY transposed into LDS [d][token] (stride 144 shorts = 288 B:
// us8 reads 16B-aligned, 64-lane b128 bank-group map (2d+tc)&7 is uniform),
// then contiguous us8 reads -> 16B global stores. Compile-time indices only.
#define EPI_STRIDE 136  // shorts; row-major epilogue rows (q/k path)
#define VT_STRIDE 144   // shorts; transposed V epilogue rows (288 B, 16B-aligned)
__global__ __launch_bounds__(256) void gemm_qkv(const ushort* __restrict__ A,
                                                const ushort* __restrict__ Bt,
                                                ushort* __restrict__ qo,
                                                ushort* __restrict__ ko,
                                                ushort* __restrict__ vo,
                                                int K) {
  __shared__ alignas(16) ushort smem[128 * VT_STRIDE];
  ushort* As = smem;          // 128*64
  ushort* Bs = smem + 8192;   // 128*64
  const int tid = threadIdx.x;
  const int lane = tid & 63;
  const int wid = tid >> 6;
  const int wm = wid >> 1, wn = wid & 1;
  const int quad = lane >> 4, l16 = lane & 15;
  const int bm = blockIdx.y * 128, bn = blockIdx.x * 128;

  fx4 acc[4][4];
  for (int i = 0; i < 4; ++i)
    for (int j = 0; j < 4; ++j) acc[i][j] = (fx4){0.f, 0.f, 0.f, 0.f};

  const int r8 = lane >> 3, s8 = lane & 7;
  for (int k0 = 0; k0 < K; k0 += 64) {
    for (int i = 0; i < 4; ++i) {
      int m = i * 32 + wid * 8 + r8;
      int c = s8 ^ (m & 7);
      gld_lds16(A + (size_t)(bm + m) * K + k0 + c * 8, As + (i * 32 + wid * 8) * 64);
      gld_lds16(Bt + (size_t)(bn + m) * K + k0 + c * 8, Bs + (i * 32 + wid * 8) * 64);
    }
    __syncthreads();
    for (int ks = 0; ks < 2; ++ks) {
      bs8 af[4], bf[4];
      for (int mt = 0; mt < 4; ++mt) {
        int m = wm * 64 + mt * 16 + l16;
        int c = ks * 4 + quad;
        int slot = c ^ (m & 7);
        af[mt] = *(const bs8*)(As + m * 64 + slot * 8);
      }
      for (int nt = 0; nt < 4; ++nt) {
        int n = wn * 64 + nt * 16 + l16;
        int c = ks * 4 + quad;
        int slot = c ^ (n & 7);
        bf[nt] = *(const bs8*)(Bs + n * 64 + slot * 8);
      }
      for (int mt = 0; mt < 4; ++mt)
        for (int nt = 0; nt < 4; ++nt)
          acc[mt][nt] = __builtin_amdgcn_mfma_f32_16x16x32_bf16(af[mt], bf[nt],
                                                                acc[mt][nt], 0, 0, 0);
    }
    __syncthreads();
  }

  if (bn < 2560) {
    // ---- q / k epilogue: row-major LDS round-trip, us8 stores ----
    for (int mt = 0; mt < 4; ++mt)
      for (int nt = 0; nt < 4; ++nt)
        for (int r = 0; r < 4; ++r) {
          int row = wm * 64 + mt * 16 + quad * 4 + r;
          int col = wn * 64 + nt * 16 + l16;
          smem[row * EPI_STRIDE + col] = f2b(acc[mt][nt][r]);
        }
    __syncthreads();
    const int rsel = tid >> 4;   // 0..15
    const int csel = tid & 15;   // 16B chunk within row
    for (int ii = 0; ii < 8; ++ii) {
      int row = ii * 16 + rsel;
      us8 chunk = *(const us8*)(smem + row * EPI_STRIDE + csel * 8);
      int row_g = bm + row;
      int colc = bn + csel * 8;
      if (bn < 2048) {
        *(us8*)(qo + (size_t)row_g * 2048 + colc) = chunk;
      } else {
        int b = row_g >> 11, t = row_g & 2047;
        int kc = colc - 2048;
        int gg = kc >> 7, d = kc & 127;
        *(us8*)(ko + ((size_t)(b * KVH + gg) * TT + t) * HD + d) = chunk;
      }
    }
  } else {
    // ---- V epilogue: store acc transposed [d_local][token_local], stride 144 ----
    for (int mt = 0; mt < 4; ++mt)
      for (int nt = 0; nt < 4; ++nt)
        for (int r = 0; r < 4; ++r) {
          int row = wm * 64 + mt * 16 + quad * 4 + r;   // token_local
          int col = wn * 64 + nt * 16 + l16;            // d_local
          smem[col * VT_STRIDE + row] = f2b(acc[mt][nt][r]);
        }
    __syncthreads();
    const int gg = (bn - 2560) >> 7;
    const int b = bm >> 11;        // 128-row tile never straddles b (2048%128==0)
    const int t0 = bm & 2047;
    const int tc = tid & 15;       // token chunk (8 tokens)
    const int drow = tid >> 4;     // 0..15
    const ushort* vrow_base = vo + (size_t)(b * KVH + gg) * HD * TT;
    for (int it = 0; it < 8; ++it) {
      int d = it * 16 + drow;
      us8 chunk = *(const us8*)(smem + d * VT_STRIDE + tc * 8);
      *(us8*)((ushort*)vrow_base + (size_t)d * TT + t0 + tc * 8) = chunk;
    }
  }
}

// ---------------- output-projection GEMM: fp32 out ----------------
__global__ __launch_bounds__(256) void gemm_out(const ushort* __restrict__ A,
                                                const ushort* __restrict__ Bt,
                                                float* __restrict__ Cout,
                                                int N, int K) {
  __shared__ alignas(16) ushort smem[128 * EPI_STRIDE];
  ushort* As = smem;
  ushort* Bs = smem + 8192;
  const int tid = threadIdx.x;
  const int lane = tid & 63;
  const int wid = tid >> 6;
  const int wm = wid >> 1, wn = wid & 1;
  const int quad = lane >> 4, l16 = lane & 15;
  const int bm = blockIdx.y * 128, bn = blockIdx.x * 128;

  fx4 acc[4][4];
  for (int i = 0; i < 4; ++i)
    for (int j = 0; j < 4; ++j) acc[i][j] = (fx4){0.f, 0.f, 0.f, 0.f};

  const int r8 = lane >> 3, s8 = lane & 7;
  for (int k0 = 0; k0 < K; k0 += 64) {
    for (int i = 0; i < 4; ++i) {
      int m = i * 32 + wid * 8 + r8;
      int c = s8 ^ (m & 7);
      gld_lds16(A + (size_t)(bm + m) * K + k0 + c * 8, As + (i * 32 + wid * 8) * 64);
      gld_lds16(Bt + (size_t)(bn + m) * K + k0 + c * 8, Bs + (i * 32 + wid * 8) * 64);
    }
    __syncthreads();
    for (int ks = 0; ks < 2; ++ks) {
      bs8 af[4], bf[4];
      for (int mt = 0; mt < 4; ++mt) {
        int m = wm * 64 + mt * 16 + l16;
        int c = ks * 4 + quad;
        int slot = c ^ (m & 7);
        af[mt] = *(const bs8*)(As + m * 64 + slot * 8);
      }
      for (int nt = 0; nt < 4; ++nt) {
        int n = wn * 64 + nt * 16 + l16;
        int c = ks * 4 + quad;
        int slot = c ^ (n & 7);
        bf[nt] = *(const bs8*)(Bs + n * 64 + slot * 8);
      }
      for (int mt = 0; mt < 4; ++mt)
        for (int nt = 0; nt < 4; ++nt)
          acc[mt][nt] = __builtin_amdgcn_mfma_f32_16x16x32_bf16(af[mt], bf[nt],
                                                                acc[mt][nt], 0, 0, 0);
    }
    __syncthreads();
  }

  // ---- epilogue: bf16 LDS round-trip, fp32 vector stores ----
  for (int mt = 0; mt < 4; ++mt)
    for (int nt = 0; nt < 4; ++nt)
      for (int r = 0; r < 4; ++r) {
        int row = wm * 64 + mt * 16 + quad * 4 + r;
        int col = wn * 64 + nt * 16 + l16;
        smem[row * EPI_STRIDE + col] = f2b(acc[mt][nt][r]);
      }
  __syncthreads();
  const int rsel = tid >> 4;
  const int csel = tid & 15;
  for (int ii = 0; ii < 8; ++ii) {
    int row = ii * 16 + rsel;
    us8 chunk = *(const us8*)(smem + row * EPI_STRIDE + csel * 8);
    int row_g = bm + row;
    int colc = bn + csel * 8;
    float4 lo = {b2f(chunk[0]), b2f(chunk[1]), b2f(chunk[2]), b2f(chunk[3])};
    float4 hi = {b2f(chunk[4]), b2f(chunk[5]), b2f(chunk[6]), b2f(chunk[7])};
    *(float4*)(Cout + (size_t)row_g * N + colc) = lo;
    *(float4*)(Cout + (size_t)row_g * N + colc + 4) = hi;
  }
}

// ---------------- fused causal WGQA attention, 8-wave blocks ----------------
// Verbatim proven 71.5 us version (round-1/round-4).
// 512 blocks x 512 threads. Block = 128-query chunk; wave owns 16 queries.
//  * K/V double-buffered LDS, tile j+1 DMAs issued before counted vmcnt(4).
//  * defer-max (T13), exp2 folding, chunk-XOR swizzles, setprio around MFMA.
//  * complementary qt pairing keeps per-CU iteration count uniform (34).
// Ledger: 32q/wave (r2) -> concurrency-bound; V-from-L2 (r3) -> latency-bound;
// split-key partials (r5) -> VGPR spill. This structure is the local optimum.
__global__ __launch_bounds__(512, 4) void attn_kernel(const ushort* __restrict__ qb,
                                                      const ushort* __restrict__ kb,
                                                      const ushort* __restrict__ vt,
                                                      ushort* __restrict__ yb,
                                                      const float* __restrict__ wlog) {
  __shared__ alignas(16) ushort Ks[2][64 * 128];   // [buf][key][d], chunk-swizzled
  __shared__ alignas(16) ushort Vs[2][128 * 64];   // [buf][d][key], chunk-swizzled
  __shared__ alignas(16) ushort Ps[128 * 64];      // [q][key], chunk-XOR swizzled

  const int bid = blockIdx.x;
  const int qt = (bid & 256) ? (bid & 15) : 15 - (bid & 15);
  const int h = (bid >> 4) & 15;
  const int b = bid >> 8;
  const int g = h >> 2;
  const int tid = threadIdx.x;
  const int lane = tid & 63;
  const int wid = tid >> 6;        // 0..7
  const int quad = lane >> 4;
  const int l16 = lane & 15;
  const int qw = qt * 128 + wid * 16;   // wave's first query

  const float scale = wlog[g] * 0.08838834764831845f;  // 1/sqrt(128)
  const float sc2 = scale * 1.4426950408889634f;       // * log2(e)

  const ushort* kbase = kb + (size_t)(b * KVH + g) * TT * HD;
  const ushort* vbase = vt + (size_t)(b * KVH + g) * HD * TT;

  // persistent staging pointers; each thread stages 2 K-slots + 2 V-slots
  const ushort* kp;
  const ushort* vp;
  {
    int keyr = wid * 4 + (lane >> 4);          // 0..31
    int si = lane & 15;
    int ck = (si & 8) | ((si ^ keyr) & 7);
    kp = kbase + (size_t)keyr * HD + ck * 8;
    int dr = wid * 8 + (lane >> 3);            // 0..63
    int s8 = lane & 7;
    int cv = s8 ^ (dr & 7);
    vp = vbase + (size_t)dr * TT + cv * 8;
  }

  // ---- prologue: stage tile 0 into buffer 0 (DMA runs under Q-load) ----
  gld_lds16(kp, &Ks[0][wid * 512]);
  gld_lds16(kp + 32 * HD, &Ks[0][4096 + wid * 512]);
  gld_lds16(vp, &Vs[0][wid * 512]);
  gld_lds16(vp + 64 * TT, &Vs[0][4096 + wid * 512]);
  kp += 64 * HD;
  vp += 64;

  // Q fragments in registers (B-operand of S^T = K * Q^T)
  bs8 qf[4];
  {
    int q = qw + l16;
    const ushort* qrow = qb + ((size_t)(b * TT + q)) * DM + h * HD;
#pragma unroll
    for (int ks = 0; ks < 4; ++ks)
      qf[ks] = *(const bs8*)(qrow + ks * 32 + quad * 8);
  }

  float m_i = -INFINITY;  // running max of RAW logits
  float l_i = 0.f;
  fx4 o[8];
#pragma unroll
  for (int i = 0; i < 8; ++i) o[i] = (fx4){0.f, 0.f, 0.f, 0.f};

  const int jmax = 2 * qt + 1;
  for (int j = 0; j <= jmax; ++j) {
    const int cur = j & 1;
    // ---- issue NEXT tile's DMAs first, then wait only for tile j ----
    if (j < jmax) {
      const int nxt = cur ^ 1;
      gld_lds16(kp, &Ks[nxt][wid * 512]);
      gld_lds16(kp + 32 * HD, &Ks[nxt][4096 + wid * 512]);
      gld_lds16(vp, &Vs[nxt][wid * 512]);
      gld_lds16(vp + 64 * TT, &Vs[nxt][4096 + wid * 512]);
      kp += 64 * HD;
      vp += 64;
      asm volatile("s_waitcnt vmcnt(4)" ::: "memory");  // tile j done, j+1 in flight
    } else {
      asm volatile("s_waitcnt vmcnt(0)" ::: "memory");
    }
    __builtin_amdgcn_s_barrier();

    if (j * 64 <= qw + 15) {  // wave has at least one unmasked key
      const ushort* Kc = Ks[cur];
      const ushort* Vc = Vs[cur];
      // ---- S^T = K * Q^T  (64 keys x 16 queries), fp32 acc ----
      fx4 s[4];
#pragma unroll
      for (int mt = 0; mt < 4; ++mt) s[mt] = (fx4){0.f, 0.f, 0.f, 0.f};
      __builtin_amdgcn_s_setprio(1);
#pragma unroll
      for (int mt = 0; mt < 4; ++mt) {
        bs8 a[4];
        int key = mt * 16 + l16;
#pragma unroll
        for (int ks = 0; ks < 4; ++ks) {
          int c = ks * 4 + quad;
          int slot = (c & 8) | ((c ^ key) & 7);
          a[ks] = *(const bs8*)(Kc + key * 128 + slot * 8);
        }
#pragma unroll
        for (int ks = 0; ks < 4; ++ks)
          s[mt] = __builtin_amdgcn_mfma_f32_16x16x32_bf16(a[ks], qf[ks],
                                                          s[mt], 0, 0, 0);
      }
      __builtin_amdgcn_s_setprio(0);

      // ---- causal mask: needed iff tile max key > wave min query ----
      const int q = qw + l16;
      if (j * 64 + 63 > qw) {
#pragma unroll
        for (int mt = 0; mt < 4; ++mt)
#pragma unroll
          for (int r = 0; r < 4; ++r) {
            int key = j * 64 + mt * 16 + quad * 4 + r;
            if (key > q) s[mt][r] = -1e30f;
          }
      }
      float mx = s[0][0];
#pragma unroll
      for (int mt = 0; mt < 4; ++mt)
#pragma unroll
        for (int r = 0; r < 4; ++r) mx = fmaxf(mx, s[mt][r]);
      mx = fmaxf(mx, __shfl_xor(mx, 16));
      mx = fmaxf(mx, __shfl_xor(mx, 32));

      // ---- defer-max: only rescale when the max actually grows (>8 scaled) ----
      if (!__all((mx - m_i) * scale <= 8.0f)) {
        float m_new = fmaxf(m_i, mx);
        float alpha = EXP2((m_i - m_new) * sc2);
        l_i *= alpha;
#pragma unroll
        for (int dmt = 0; dmt < 8; ++dmt)
#pragma unroll
          for (int r = 0; r < 4; ++r) o[dmt][r] *= alpha;
        m_i = m_new;
      }
      float negb = -m_i * sc2;
      float sum = 0.f;
#pragma unroll
      for (int mt = 0; mt < 4; ++mt)
#pragma unroll
        for (int r = 0; r < 4; ++r) {
          float pv = EXP2(fmaf(s[mt][r], sc2, negb));
          s[mt][r] = pv;
          sum += pv;
        }
      sum += __shfl_xor(sum, 16);
      sum += __shfl_xor(sum, 32);
      l_i += sum;

      // P (bf16) to LDS, [q][key] stride 64 with chunk-XOR swizzle;
      // wave touches only its own 16 rows -> no barrier needed
      int qrow = wid * 16 + l16;
      int sw = l16 & 7;
#pragma unroll
      for (int mt = 0; mt < 4; ++mt) {
        us4 pw = {f2b(s[mt][0]), f2b(s[mt][1]), f2b(s[mt][2]), f2b(s[mt][3])};
        int chunk = mt * 2 + (quad >> 1);
        *(us4*)(Ps + qrow * 64 + ((chunk ^ sw) << 3) + ((quad & 1) << 2)) = pw;
      }

      // ---- O^T += V^T * P^T  (no barrier: wave reads only its own P rows) ----
#pragma unroll
      for (int ks = 0; ks < 2; ++ks) {
        bs8 pb = *(const bs8*)(Ps + qrow * 64 + (((ks * 4 + quad) ^ sw) << 3));
        __builtin_amdgcn_s_setprio(1);
#pragma unroll
        for (int dmt = 0; dmt < 8; ++dmt) {
          int d = dmt * 16 + l16;
          int c = ks * 4 + quad;
          int slot = c ^ (d & 7);
          bs8 va = *(const bs8*)(Vc + d * 64 + slot * 8);
          o[dmt] = __builtin_amdgcn_mfma_f32_16x16x32_bf16(va, pb, o[dmt], 0, 0, 0);
        }
        __builtin_amdgcn_s_setprio(0);
      }
    }
    // all my LDS reads of buf[cur] must be complete before signaling; the
    // barrier then licenses other waves' DMAs for tile j+2 to overwrite it
    asm volatile("s_waitcnt lgkmcnt(0)" ::: "memory");
    __builtin_amdgcn_s_barrier();
  }

  // ---- epilogue: normalize and write y (bf16, [b][t][h*128+d]) ----
  {
    float inv = 1.0f / l_i;
    int q = qw + l16;
    ushort* yrow = yb + ((size_t)(b * TT + q)) * DM + h * HD;
#pragma unroll
    for (int dmt = 0; dmt < 8; ++dmt) {
      us4 w = {f2b(o[dmt][0] * inv), f2b(o[dmt][1] * inv),
               f2b(o[dmt][2] * inv), f2b(o[dmt][3] * inv)};
      *(us4*)(yrow + dmt * 16 + quad * 4) = w;
    }
  }
}

// ---------------- launch ----------------
extern "C" void kernel_launch(void* const* d_in, const int* in_sizes, int n_in,
                              void* d_out, int out_size, void* d_ws, size_t ws_size,
                              hipStream_t stream) {
  const float* x = (const float*)d_in[0];
  // d_in[1] = attn_mask: ignored (exact causal mask computed analytically)
  const float* Wq = (const float*)d_in[2];
  const float* Wk = (const float*)d_in[3];
  const float* Wv = (const float*)d_in[4];
  const float* Wo = (const float*)d_in[5];
  const float* wlog = (const float*)d_in[6];
  // d_in[7] = weight_values: unused by the reference

  char* ws = (char*)d_ws;
  ushort* xb = (ushort*)ws;     ws += (size_t)4096 * 2048 * 2;
  ushort* Wqkvt = (ushort*)ws;  ws += (size_t)3072 * 2048 * 2;
  ushort* Wot = (ushort*)ws;    ws += (size_t)2048 * 2048 * 2;
  ushort* qbuf = (ushort*)ws;   ws += (size_t)4096 * 2048 * 2;
  ushort* kbuf = (ushort*)ws;   ws += (size_t)2 * KVH * 2048 * 128 * 2;
  ushort* vbuf = (ushort*)ws;   ws += (size_t)2 * KVH * 2048 * 128 * 2;
  ushort* ybuf = (ushort*)ws;   ws += (size_t)4096 * 2048 * 2;

  prep_kernel<<<dim3(96, 64, 3), dim3(32, 8), 0, stream>>>(
      x, Wq, Wk, Wv, Wo, xb, Wqkvt, Wot);
  gemm_qkv<<<dim3(24, 32), 256, 0, stream>>>(xb, Wqkvt, qbuf, kbuf, vbuf, 2048);
  attn_kernel<<<512, 512, 0, stream>>>(qbuf, kbuf, vbuf, ybuf, wlog);
  gemm_out<<<dim3(16, 32), 256, 0, stream>>>(ybuf, Wot, (float*)d_out, 2048, 2048);
}

// Round 9
// 297.954 us; speedup vs baseline: 1.4297x; 1.0314x over previous
//
#include <hip/hip_runtime.h>
#include <hip/hip_bf16.h>

#define TT 2048
#define DM 2048
#define NH 16
#define KVH 4
#define HD 128

typedef __attribute__((ext_vector_type(8))) short bs8;
typedef __attribute__((ext_vector_type(4))) float fx4;
typedef __attribute__((ext_vector_type(4))) unsigned short us4;
typedef __attribute__((ext_vector_type(8))) unsigned short us8;

#if __has_builtin(__builtin_amdgcn_exp2f)
#define EXP2(x) __builtin_amdgcn_exp2f(x)
#else
#define EXP2(x) exp2f(x)
#endif

__device__ inline unsigned short f2b(float f) {
  __hip_bfloat16 h = __float2bfloat16(f);
  return *reinterpret_cast<unsigned short*>(&h);
}

__device__ inline float b2f(unsigned short u) {
  unsigned int v = ((unsigned int)u) << 16;
  return *reinterpret_cast<float*>(&v);
}

__device__ inline void gld_lds16(const ushort* g, ushort* l) {
  __builtin_amdgcn_global_load_lds(
      (const __attribute__((address_space(1))) void*)g,
      (__attribute__((address_space(3))) void*)l,
      16, 0, 0);
}

// ---------------- prep: weight transposes + x cast, one dispatch ----------------
// z=0: Wqkvt[3072][2048] from Wq|Wk|Wv   z=1: Wot[2048][2048] from Wo
// z=2: x fp32 -> bf16 cast (linear)
__global__ __launch_bounds__(256) void prep_kernel(
    const float* __restrict__ x, const float* __restrict__ Wq,
    const float* __restrict__ Wk, const float* __restrict__ Wv,
    const float* __restrict__ Wo, ushort* __restrict__ xb,
    ushort* __restrict__ Wqkvt, ushort* __restrict__ Wot) {
  int tx = threadIdx.x, ty = threadIdx.y;  // block (32,8)
  if (blockIdx.z == 2) {
    int lin = (blockIdx.y * 96 + blockIdx.x) * 256 + ty * 32 + tx;
#pragma unroll
    for (int it = 0; it < 2; ++it) {
      int i = lin + it * (6144 * 256);
      if (i < (TT * 2 * DM) / 4) {
        float4 v = ((const float4*)x)[i];
        us4 o = {f2b(v.x), f2b(v.y), f2b(v.z), f2b(v.w)};
        ((us4*)xb)[i] = o;
      }
    }
    return;
  }
  __shared__ float t[32][33];
  int n0 = blockIdx.x * 32, k0 = blockIdx.y * 32;
  if (blockIdx.z == 0) {
    const float* src;
    int srcN, col0;
    if (n0 < 2048) { src = Wq; srcN = 2048; col0 = n0; }
    else if (n0 < 2560) { src = Wk; srcN = 512; col0 = n0 - 2048; }
    else { src = Wv; srcN = 512; col0 = n0 - 2560; }
    for (int jj = 0; jj < 4; ++jj)
      t[ty + jj * 8][tx] = src[(size_t)(k0 + ty + jj * 8) * srcN + col0 + tx];
    __syncthreads();
    for (int jj = 0; jj < 4; ++jj)
      Wqkvt[(size_t)(n0 + ty + jj * 8) * 2048 + k0 + tx] = f2b(t[tx][ty + jj * 8]);
  } else {
    if (n0 >= 2048) return;
    for (int jj = 0; jj < 4; ++jj)
      t[ty + jj * 8][tx] = Wo[(size_t)(k0 + ty + jj * 8) * 2048 + n0 + tx];
    __syncthreads();
    for (int jj = 0; jj < 4; ++jj)
      Wot[(size_t)(n0 + ty + jj * 8) * 2048 + k0 + tx] = f2b(t[tx][ty + jj * 8]);
  }
}

// ---------------- fused QKV GEMM: [4096 x 3072] = xb * Wqkvt^T ----------------
// ROUND-9: 256x256 tile, BK=64, 8 waves (2M x 4N), 128 KB LDS double-buffer.
// Rationale: the 128-tile 2-barrier structure is at its documented ~structural
// ceiling (MfmaUtil ~24%); 256-tile doubles arithmetic intensity per staged
// byte, uses ONE barrier per K-step, and prefetches tile kt+1's 8 DMAs at the
// start of tile kt so the vmcnt(0) wait lands ~700 cyc after issue.
// Per-wave output 128x64 (acc 8x4 fx4 = 128 VGPR); launch_bounds(512,2) caps
// VGPR at 256 (round-5 spill lesson). Chunk-XOR swizzle identical to the
// verified 128-tile scheme. Epilogue: two column-half LDS passes; V written
// directly transposed [b,g,d,t] (compile-time vector indices only).
#define EPI_STRIDE 136  // shorts; row stride for 128-col epilogue passes
#define VT_STRIDE 264   // shorts; d-row stride for transposed V passes (528 B)
__global__ __launch_bounds__(512, 2) void gemm_qkv(const ushort* __restrict__ A,
                                                   const ushort* __restrict__ Bt,
                                                   ushort* __restrict__ qo,
                                                   ushort* __restrict__ ko,
                                                   ushort* __restrict__ vo,
                                                   int K) {
  __shared__ alignas(16) ushort smem[65536];  // 128 KB
  // As buf c: smem + c*16384 ; Bs buf c: smem + 32768 + c*16384
  const int tid = threadIdx.x;
  const int lane = tid & 63;
  const int wid = tid >> 6;        // 0..7
  const int wm = wid >> 2;         // 0..1  (output row half)
  const int wn = wid & 3;          // 0..3  (output col quarter)
  const int quad = lane >> 4, l16 = lane & 15;
  const int swl = l16 & 7;
  const int bm = blockIdx.y * 256, bn = blockIdx.x * 256;
  const int r8 = lane >> 3, s8 = lane & 7;
  const int cst = s8 ^ r8;         // staging chunk swizzle (m&7 == r8)

  fx4 acc[8][4];
#pragma unroll
  for (int i = 0; i < 8; ++i)
#pragma unroll
    for (int j = 0; j < 4; ++j) acc[i][j] = (fx4){0.f, 0.f, 0.f, 0.f};

  // per-thread staging base pointers (stripe s adds s*64 rows)
  const ushort* apA = A + (size_t)(bm + wid * 8 + r8) * K + cst * 8;
  const ushort* apB = Bt + (size_t)(bn + wid * 8 + r8) * K + cst * 8;
  const int dofs = (wid * 8) * 64;  // LDS dest offset within buffer (lane adds 16B)

  // ---- prologue: stage tile 0 into buf 0 ----
#pragma unroll
  for (int s = 0; s < 4; ++s) {
    gld_lds16(apA + (size_t)(s * 64) * K, smem + dofs + s * 4096);
    gld_lds16(apB + (size_t)(s * 64) * K, smem + 32768 + dofs + s * 4096);
  }
  asm volatile("s_waitcnt vmcnt(0)" ::: "memory");
  __builtin_amdgcn_s_barrier();

  const int NT = K >> 6;
  for (int kt = 0; kt < NT; ++kt) {
    const int cur = kt & 1, nxt = cur ^ 1;
    const ushort* As = smem + cur * 16384;
    const ushort* Bs = smem + 32768 + cur * 16384;
    if (kt + 1 < NT) {
      const ushort* sa = apA + (kt + 1) * 64;
      const ushort* sb = apB + (kt + 1) * 64;
      ushort* dA = smem + nxt * 16384 + dofs;
      ushort* dB = smem + 32768 + nxt * 16384 + dofs;
#pragma unroll
      for (int s = 0; s < 4; ++s) {
        gld_lds16(sa + (size_t)(s * 64) * K, dA + s * 4096);
        gld_lds16(sb + (size_t)(s * 64) * K, dB + s * 4096);
      }
    }
#pragma unroll
    for (int p = 0; p < 4; ++p) {
      const int ks = p >> 1, mh = p & 1;
      const int so = (((ks * 4 + quad) ^ swl) << 3);  // swizzled 16B slot (shorts)
      bs8 bf[4], af[4];
#pragma unroll
      for (int nt = 0; nt < 4; ++nt) {
        int n = wn * 64 + nt * 16 + l16;
        bf[nt] = *(const bs8*)(Bs + n * 64 + so);
      }
#pragma unroll
      for (int i = 0; i < 4; ++i) {
        int m = wm * 128 + (mh * 4 + i) * 16 + l16;
        af[i] = *(const bs8*)(As + m * 64 + so);
      }
      __builtin_amdgcn_s_setprio(1);
#pragma unroll
      for (int i = 0; i < 4; ++i)
#pragma unroll
        for (int nt = 0; nt < 4; ++nt)
          acc[mh * 4 + i][nt] = __builtin_amdgcn_mfma_f32_16x16x32_bf16(
              af[i], bf[nt], acc[mh * 4 + i][nt], 0, 0, 0);
      __builtin_amdgcn_s_setprio(0);
    }
    if (kt + 1 < NT) asm volatile("s_waitcnt vmcnt(0)" ::: "memory");
    __builtin_amdgcn_s_barrier();
  }

  // ---- epilogue: two 128-column passes through LDS ----
  if (bn < 2560) {
    // q / k: row-major [256][136] per pass
#pragma unroll
    for (int h = 0; h < 2; ++h) {
      if ((wn >> 1) == h) {
#pragma unroll
        for (int mt = 0; mt < 8; ++mt)
#pragma unroll
          for (int nt = 0; nt < 4; ++nt)
#pragma unroll
            for (int r = 0; r < 4; ++r) {
              int row = wm * 128 + mt * 16 + quad * 4 + r;      // 0..255
              int col = (wn & 1) * 64 + nt * 16 + l16;          // 0..127
              smem[row * EPI_STRIDE + col] = f2b(acc[mt][nt][r]);
            }
      }
      __builtin_amdgcn_s_barrier();
      const int rsel = tid >> 4;   // 0..31
      const int csel = tid & 15;   // 16B chunk
      for (int ii = 0; ii < 8; ++ii) {
        int row = ii * 32 + rsel;
        us8 chunk = *(const us8*)(smem + row * EPI_STRIDE + csel * 8);
        int row_g = bm + row;
        int colc = bn + h * 128 + csel * 8;
        if (bn < 2048) {
          *(us8*)(qo + (size_t)row_g * 2048 + colc) = chunk;
        } else {
          int b = row_g >> 11, t = row_g & 2047;
          int kc = colc - 2048;
          int gg = kc >> 7, d = kc & 127;
          *(us8*)(ko + ((size_t)(b * KVH + gg) * TT + t) * HD + d) = chunk;
        }
      }
      __builtin_amdgcn_s_barrier();
    }
  } else {
    // V: transposed [d_local 0..127][token 0..255] per pass, stride 264
    const int b = bm >> 11;        // 256-row tile never straddles b (2048%256==0)
    const int t0 = bm & 2047;
#pragma unroll
    for (int h = 0; h < 2; ++h) {
      if ((wn >> 1) == h) {
#pragma unroll
        for (int mt = 0; mt < 8; ++mt)
#pragma unroll
          for (int nt = 0; nt < 4; ++nt)
#pragma unroll
            for (int r = 0; r < 4; ++r) {
              int row = wm * 128 + mt * 16 + quad * 4 + r;      // token_local
              int col = (wn & 1) * 64 + nt * 16 + l16;          // d_local
              smem[col * VT_STRIDE + row] = f2b(acc[mt][nt][r]);
            }
      }
      __builtin_amdgcn_s_barrier();
      const int tc = tid & 31;     // token chunk (8 tokens)
      const int dr = tid >> 5;     // 0..15
      for (int it = 0; it < 8; ++it) {
        int d_local = it * 16 + dr;                        // 0..127
        us8 chunk = *(const us8*)(smem + d_local * VT_STRIDE + tc * 8);
        int vc = (bn - 2560) + h * 128 + d_local;          // 0..511
        int gg = vc >> 7, dd = vc & 127;
        *(us8*)(vo + ((size_t)(b * KVH + gg) * HD + dd) * TT + t0 + tc * 8) = chunk;
      }
      __builtin_amdgcn_s_barrier();
    }
  }
}

// ---------------- output-projection GEMM: fp32 out (unchanged 128-tile) ----------------
__global__ __launch_bounds__(256) void gemm_out(const ushort* __restrict__ A,
                                                const ushort* __restrict__ Bt,
                                                float* __restrict__ Cout,
                                                int N, int K) {
  __shared__ alignas(16) ushort smem[128 * EPI_STRIDE];
  ushort* As = smem;
  ushort* Bs = smem + 8192;
  const int tid = threadIdx.x;
  const int lane = tid & 63;
  const int wid = tid >> 6;
  const int wm = wid >> 1, wn = wid & 1;
  const int quad = lane >> 4, l16 = lane & 15;
  const int bm = blockIdx.y * 128, bn = blockIdx.x * 128;

  fx4 acc[4][4];
  for (int i = 0; i < 4; ++i)
    for (int j = 0; j < 4; ++j) acc[i][j] = (fx4){0.f, 0.f, 0.f, 0.f};

  const int r8 = lane >> 3, s8 = lane & 7;
  for (int k0 = 0; k0 < K; k0 += 64) {
    for (int i = 0; i < 4; ++i) {
      int m = i * 32 + wid * 8 + r8;
      int c = s8 ^ (m & 7);
      gld_lds16(A + (size_t)(bm + m) * K + k0 + c * 8, As + (i * 32 + wid * 8) * 64);
      gld_lds16(Bt + (size_t)(bn + m) * K + k0 + c * 8, Bs + (i * 32 + wid * 8) * 64);
    }
    __syncthreads();
    for (int ks = 0; ks < 2; ++ks) {
      bs8 af[4], bf[4];
      for (int mt = 0; mt < 4; ++mt) {
        int m = wm * 64 + mt * 16 + l16;
        int c = ks * 4 + quad;
        int slot = c ^ (m & 7);
        af[mt] = *(const bs8*)(As + m * 64 + slot * 8);
      }
      for (int nt = 0; nt < 4; ++nt) {
        int n = wn * 64 + nt * 16 + l16;
        int c = ks * 4 + quad;
        int slot = c ^ (n & 7);
        bf[nt] = *(const bs8*)(Bs + n * 64 + slot * 8);
      }
      for (int mt = 0; mt < 4; ++mt)
        for (int nt = 0; nt < 4; ++nt)
          acc[mt][nt] = __builtin_amdgcn_mfma_f32_16x16x32_bf16(af[mt], bf[nt],
                                                                acc[mt][nt], 0, 0, 0);
    }
    __syncthreads();
  }

  // ---- epilogue: bf16 LDS round-trip, fp32 vector stores ----
  for (int mt = 0; mt < 4; ++mt)
    for (int nt = 0; nt < 4; ++nt)
      for (int r = 0; r < 4; ++r) {
        int row = wm * 64 + mt * 16 + quad * 4 + r;
        int col = wn * 64 + nt * 16 + l16;
        smem[row * EPI_STRIDE + col] = f2b(acc[mt][nt][r]);
      }
  __syncthreads();
  const int rsel = tid >> 4;
  const int csel = tid & 15;
  for (int ii = 0; ii < 8; ++ii) {
    int row = ii * 16 + rsel;
    us8 chunk = *(const us8*)(smem + row * EPI_STRIDE + csel * 8);
    int row_g = bm + row;
    int colc = bn + csel * 8;
    float4 lo = {b2f(chunk[0]), b2f(chunk[1]), b2f(chunk[2]), b2f(chunk[3])};
    float4 hi = {b2f(chunk[4]), b2f(chunk[5]), b2f(chunk[6]), b2f(chunk[7])};
    *(float4*)(Cout + (size_t)row_g * N + colc) = lo;
    *(float4*)(Cout + (size_t)row_g * N + colc + 4) = hi;
  }
}

// ---------------- fused causal WGQA attention, 8-wave blocks ----------------
// Verbatim proven 70.5 us version. Ledger: 32q/wave (r2) concurrency-bound;
// V-from-L2 (r3) latency-bound; split-key partials (r5) VGPR spill. Local opt.
__global__ __launch_bounds__(512, 4) void attn_kernel(const ushort* __restrict__ qb,
                                                      const ushort* __restrict__ kb,
                                                      const ushort* __restrict__ vt,
                                                      ushort* __restrict__ yb,
                                                      const float* __restrict__ wlog) {
  __shared__ alignas(16) ushort Ks[2][64 * 128];   // [buf][key][d], chunk-swizzled
  __shared__ alignas(16) ushort Vs[2][128 * 64];   // [buf][d][key], chunk-swizzled
  __shared__ alignas(16) ushort Ps[128 * 64];      // [q][key], chunk-XOR swizzled

  const int bid = blockIdx.x;
  const int qt = (bid & 256) ? (bid & 15) : 15 - (bid & 15);
  const int h = (bid >> 4) & 15;
  const int b = bid >> 8;
  const int g = h >> 2;
  const int tid = threadIdx.x;
  const int lane = tid & 63;
  const int wid = tid >> 6;        // 0..7
  const int quad = lane >> 4;
  const int l16 = lane & 15;
  const int qw = qt * 128 + wid * 16;   // wave's first query

  const float scale = wlog[g] * 0.08838834764831845f;  // 1/sqrt(128)
  const float sc2 = scale * 1.4426950408889634f;       // * log2(e)

  const ushort* kbase = kb + (size_t)(b * KVH + g) * TT * HD;
  const ushort* vbase = vt + (size_t)(b * KVH + g) * HD * TT;

  // persistent staging pointers; each thread stages 2 K-slots + 2 V-slots
  const ushort* kp;
  const ushort* vp;
  {
    int keyr = wid * 4 + (lane >> 4);          // 0..31
    int si = lane & 15;
    int ck = (si & 8) | ((si ^ keyr) & 7);
    kp = kbase + (size_t)keyr * HD + ck * 8;
    int dr = wid * 8 + (lane >> 3);            // 0..63
    int s8 = lane & 7;
    int cv = s8 ^ (dr & 7);
    vp = vbase + (size_t)dr * TT + cv * 8;
  }

  // ---- prologue: stage tile 0 into buffer 0 (DMA runs under Q-load) ----
  gld_lds16(kp, &Ks[0][wid * 512]);
  gld_lds16(kp + 32 * HD, &Ks[0][4096 + wid * 512]);
  gld_lds16(vp, &Vs[0][wid * 512]);
  gld_lds16(vp + 64 * TT, &Vs[0][4096 + wid * 512]);
  kp += 64 * HD;
  vp += 64;

  // Q fragments in registers (B-operand of S^T = K * Q^T)
  bs8 qf[4];
  {
    int q = qw + l16;
    const ushort* qrow = qb + ((size_t)(b * TT + q)) * DM + h * HD;
#pragma unroll
    for (int ks = 0; ks < 4; ++ks)
      qf[ks] = *(const bs8*)(qrow + ks * 32 + quad * 8);
  }

  float m_i = -INFINITY;  // running max of RAW logits
  float l_i = 0.f;
  fx4 o[8];
#pragma unroll
  for (int i = 0; i < 8; ++i) o[i] = (fx4){0.f, 0.f, 0.f, 0.f};

  const int jmax = 2 * qt + 1;
  for (int j = 0; j <= jmax; ++j) {
    const int cur = j & 1;
    // ---- issue NEXT tile's DMAs first, then wait only for tile j ----
    if (j < jmax) {
      const int nxt = cur ^ 1;
      gld_lds16(kp, &Ks[nxt][wid * 512]);
      gld_lds16(kp + 32 * HD, &Ks[nxt][4096 + wid * 512]);
      gld_lds16(vp, &Vs[nxt][wid * 512]);
      gld_lds16(vp + 64 * TT, &Vs[nxt][4096 + wid * 512]);
      kp += 64 * HD;
      vp += 64;
      asm volatile("s_waitcnt vmcnt(4)" ::: "memory");  // tile j done, j+1 in flight
    } else {
      asm volatile("s_waitcnt vmcnt(0)" ::: "memory");
    }
    __builtin_amdgcn_s_barrier();

    if (j * 64 <= qw + 15) {  // wave has at least one unmasked key
      const ushort* Kc = Ks[cur];
      const ushort* Vc = Vs[cur];
      // ---- S^T = K * Q^T  (64 keys x 16 queries), fp32 acc ----
      fx4 s[4];
#pragma unroll
      for (int mt = 0; mt < 4; ++mt) s[mt] = (fx4){0.f, 0.f, 0.f, 0.f};
      __builtin_amdgcn_s_setprio(1);
#pragma unroll
      for (int mt = 0; mt < 4; ++mt) {
        bs8 a[4];
        int key = mt * 16 + l16;
#pragma unroll
        for (int ks = 0; ks < 4; ++ks) {
          int c = ks * 4 + quad;
          int slot = (c & 8) | ((c ^ key) & 7);
          a[ks] = *(const bs8*)(Kc + key * 128 + slot * 8);
        }
#pragma unroll
        for (int ks = 0; ks < 4; ++ks)
          s[mt] = __builtin_amdgcn_mfma_f32_16x16x32_bf16(a[ks], qf[ks],
                                                          s[mt], 0, 0, 0);
      }
      __builtin_amdgcn_s_setprio(0);

      // ---- causal mask: needed iff tile max key > wave min query ----
      const int q = qw + l16;
      if (j * 64 + 63 > qw) {
#pragma unroll
        for (int mt = 0; mt < 4; ++mt)
#pragma unroll
          for (int r = 0; r < 4; ++r) {
            int key = j * 64 + mt * 16 + quad * 4 + r;
            if (key > q) s[mt][r] = -1e30f;
          }
      }
      float mx = s[0][0];
#pragma unroll
      for (int mt = 0; mt < 4; ++mt)
#pragma unroll
        for (int r = 0; r < 4; ++r) mx = fmaxf(mx, s[mt][r]);
      mx = fmaxf(mx, __shfl_xor(mx, 16));
      mx = fmaxf(mx, __shfl_xor(mx, 32));

      // ---- defer-max: only rescale when the max actually grows (>8 scaled) ----
      if (!__all((mx - m_i) * scale <= 8.0f)) {
        float m_new = fmaxf(m_i, mx);
        float alpha = EXP2((m_i - m_new) * sc2);
        l_i *= alpha;
#pragma unroll
        for (int dmt = 0; dmt < 8; ++dmt)
#pragma unroll
          for (int r = 0; r < 4; ++r) o[dmt][r] *= alpha;
        m_i = m_new;
      }
      float negb = -m_i * sc2;
      float sum = 0.f;
#pragma unroll
      for (int mt = 0; mt < 4; ++mt)
#pragma unroll
        for (int r = 0; r < 4; ++r) {
          float pv = EXP2(fmaf(s[mt][r], sc2, negb));
          s[mt][r] = pv;
          sum += pv;
        }
      sum += __shfl_xor(sum, 16);
      sum += __shfl_xor(sum, 32);
      l_i += sum;

      // P (bf16) to LDS, [q][key] stride 64 with chunk-XOR swizzle;
      // wave touches only its own 16 rows -> no barrier needed
      int qrow = wid * 16 + l16;
      int sw = l16 & 7;
#pragma unroll
      for (int mt = 0; mt < 4; ++mt) {
        us4 pw = {f2b(s[mt][0]), f2b(s[mt][1]), f2b(s[mt][2]), f2b(s[mt][3])};
        int chunk = mt * 2 + (quad >> 1);
        *(us4*)(Ps + qrow * 64 + ((chunk ^ sw) << 3) + ((quad & 1) << 2)) = pw;
      }

      // ---- O^T += V^T * P^T  (no barrier: wave reads only its own P rows) ----
#pragma unroll
      for (int ks = 0; ks < 2; ++ks) {
        bs8 pb = *(const bs8*)(Ps + qrow * 64 + (((ks * 4 + quad) ^ sw) << 3));
        __builtin_amdgcn_s_setprio(1);
#pragma unroll
        for (int dmt = 0; dmt < 8; ++dmt) {
          int d = dmt * 16 + l16;
          int c = ks * 4 + quad;
          int slot = c ^ (d & 7);
          bs8 va = *(const bs8*)(Vc + d * 64 + slot * 8);
          o[dmt] = __builtin_amdgcn_mfma_f32_16x16x32_bf16(va, pb, o[dmt], 0, 0, 0);
        }
        __builtin_amdgcn_s_setprio(0);
      }
    }
    // all my LDS reads of buf[cur] must be complete before signaling; the
    // barrier then licenses other waves' DMAs for tile j+2 to overwrite it
    asm volatile("s_waitcnt lgkmcnt(0)" ::: "memory");
    __builtin_amdgcn_s_barrier();
  }

  // ---- epilogue: normalize and write y (bf16, [b][t][h*128+d]) ----
  {
    float inv = 1.0f / l_i;
    int q = qw + l16;
    ushort* yrow = yb + ((size_t)(b * TT + q)) * DM + h * HD;
#pragma unroll
    for (int dmt = 0; dmt < 8; ++dmt) {
      us4 w = {f2b(o[dmt][0] * inv), f2b(o[dmt][1] * inv),
               f2b(o[dmt][2] * inv), f2b(o[dmt][3] * inv)};
      *(us4*)(yrow + dmt * 16 + quad * 4) = w;
    }
  }
}

// ---------------- launch ----------------
extern "C" void kernel_launch(void* const* d_in, const int* in_sizes, int n_in,
                              void* d_out, int out_size, void* d_ws, size_t ws_size,
                              hipStream_t stream) {
  const float* x = (const float*)d_in[0];
  // d_in[1] = attn_mask: ignored (exact causal mask computed analytically)
  const float* Wq = (const float*)d_in[2];
  const float* Wk = (const float*)d_in[3];
  const float* Wv = (const float*)d_in[4];
  const float* Wo = (const float*)d_in[5];
  const float* wlog = (const float*)d_in[6];
  // d_in[7] = weight_values: unused by the reference

  char* ws = (char*)d_ws;
  ushort* xb = (ushort*)ws;     ws += (size_t)4096 * 2048 * 2;
  ushort* Wqkvt = (ushort*)ws;  ws += (size_t)3072 * 2048 * 2;
  ushort* Wot = (ushort*)ws;    ws += (size_t)2048 * 2048 * 2;
  ushort* qbuf = (ushort*)ws;   ws += (size_t)4096 * 2048 * 2;
  ushort* kbuf = (ushort*)ws;   ws += (size_t)2 * KVH * 2048 * 128 * 2;
  ushort* vbuf = (ushort*)ws;   ws += (size_t)2 * KVH * 2048 * 128 * 2;
  ushort* ybuf = (ushort*)ws;   ws += (size_t)4096 * 2048 * 2;

  prep_kernel<<<dim3(96, 64, 3), dim3(32, 8), 0, stream>>>(
      x, Wq, Wk, Wv, Wo, xb, Wqkvt, Wot);
  gemm_qkv<<<dim3(12, 16), 512, 0, stream>>>(xb, Wqkvt, qbuf, kbuf, vbuf, 2048);
  attn_kernel<<<512, 512, 0, stream>>>(qbuf, kbuf, vbuf, ybuf, wlog);
  gemm_out<<<dim3(16, 32), 256, 0, stream>>>(ybuf, Wot, (float*)d_out, 2048, 2048);
}